// Round 15
// baseline (414.387 us; speedup 1.0000x reference)
//
#include <hip/hip_runtime.h>
#include <hip/hip_bf16.h>
#include <cstddef>

#define DIN 58
#define H1  300
#define H2  100

using bf16x8 = __attribute__((ext_vector_type(8))) short;
using bf16x4 = __attribute__((ext_vector_type(4))) short;
using f32x4  = __attribute__((ext_vector_type(4))) float;

__device__ inline unsigned short f2bf(float f) {
    union { float f; unsigned int u; } v; v.f = f;
    unsigned int r = v.u + 0x7fff + ((v.u >> 16) & 1);   // RNE
    return (unsigned short)(r >> 16);
}
__device__ inline float bf2f(unsigned short h) {
    union { unsigned int u; float f; } v; v.u = ((unsigned int)h) << 16;
    return v.f;
}

// ---------------- utility ----------------

__global__ void k_zero(float* __restrict__ p, long n) {
    long i = (long)blockIdx.x * 256 + threadIdx.x;
    long stride = (long)gridDim.x * 256;
    for (; i < n; i += stride) p[i] = 0.f;
}

// ---------------- degree / CSR ----------------

__global__ void k_hist(const int* __restrict__ dst, int* __restrict__ cnt, int E) {
    int e = blockIdx.x * 256 + threadIdx.x;
    if (e < E) atomicAdd(&cnt[dst[e]], 1);
}

// block scan: 1024 items/block (256 thr x 4)
__global__ __launch_bounds__(256) void k_scan1(const int* __restrict__ cnt,
                                               int* __restrict__ offs,
                                               int* __restrict__ bsum, int N) {
    __shared__ int ts[256];
    int b = blockIdx.x, t = threadIdx.x;
    int base = b * 1024 + t * 4;
    int v0 = (base + 0 < N) ? cnt[base + 0] : 0;
    int v1 = (base + 1 < N) ? cnt[base + 1] : 0;
    int v2 = (base + 2 < N) ? cnt[base + 2] : 0;
    int v3 = (base + 3 < N) ? cnt[base + 3] : 0;
    ts[t] = v0 + v1 + v2 + v3;
    __syncthreads();
    for (int off = 1; off < 256; off <<= 1) {
        int u = (t >= off) ? ts[t - off] : 0;
        __syncthreads();
        ts[t] += u;
        __syncthreads();
    }
    int ex = (t > 0) ? ts[t - 1] : 0;
    if (base + 0 < N) offs[base + 0] = ex;
    if (base + 1 < N) offs[base + 1] = ex + v0;
    if (base + 2 < N) offs[base + 2] = ex + v0 + v1;
    if (base + 3 < N) offs[base + 3] = ex + v0 + v1 + v2;
    if (t == 255) bsum[b] = ts[255];
}

__global__ __launch_bounds__(256) void k_scan2(int* __restrict__ bsum, int nb) {
    __shared__ int ts[256];
    int t = threadIdx.x;
    ts[t] = (t < nb) ? bsum[t] : 0;
    __syncthreads();
    for (int off = 1; off < 256; off <<= 1) {
        int u = (t >= off) ? ts[t - off] : 0;
        __syncthreads();
        ts[t] += u;
        __syncthreads();
    }
    if (t < nb) bsum[t] = (t > 0) ? ts[t - 1] : 0;
}

// also seeds cur = offs (for reorder's atomic cursor)
__global__ void k_scan3(int* __restrict__ offs, const int* __restrict__ bsum,
                        int* __restrict__ cur, int N) {
    int i = blockIdx.x * 256 + threadIdx.x;
    if (i < N) {
        int v = offs[i] + bsum[i >> 10];
        offs[i] = v;
        cur[i] = v;
    }
}

// reorder with inline weight: w = -rsqrt(deg[src]) * rsqrt(deg[dst])
__global__ void k_reorder2(const int* __restrict__ row, const int* __restrict__ col,
                           const int* __restrict__ cnt,
                           int* __restrict__ cur, int* __restrict__ srcS,
                           float* __restrict__ wS, int E) {
    int e = blockIdx.x * 256 + threadIdx.x;
    if (e < E) {
        int s = row[e], d = col[e];
        int p = atomicAdd(&cur[d], 1);
        float ds = (float)max(cnt[s], 1);
        float dd = (float)max(cnt[d], 1);
        srcS[p] = s;
        wS[p] = -rsqrtf(ds) * rsqrtf(dd);
    }
}

// ---------------- x -> Abf x-half (bf16 streaming convert) ----------------

__global__ void k_cvtX(const float* __restrict__ x, unsigned short* __restrict__ Abf,
                       int N) {
    int t = blockIdx.x * 256 + threadIdx.x;      // node*8 + sub
    int node = t >> 3, sub = t & 7;
    if (node >= N) return;
    bf16x8 o;
    #pragma unroll
    for (int j = 0; j < 8; ++j) {
        int c = sub * 8 + j;
        float v = (c < DIN) ? x[(size_t)node * DIN + c] : 0.f;
        o[j] = (short)f2bf(v);
    }
    *(bf16x8*)&Abf[(size_t)node * 128 + sub * 8] = o;
}

// ---------------- CSR segmented reductions ----------------

// agg1b: 8 lanes/node, gather bf16 x-half rows of Abf, write t1-half of Abf.
__global__ __launch_bounds__(256) void k_agg1b(const int* __restrict__ srcS,
                                               const float* __restrict__ wS,
                                               const int* __restrict__ offs,
                                               const int* __restrict__ cnt,
                                               unsigned short* __restrict__ Abf, int N) {
    int node = blockIdx.x * 32 + (threadIdx.x >> 3);
    int sub = threadIdx.x & 7;
    if (node >= N) return;
    int b0 = offs[node], b1 = b0 + cnt[node];
    float acc[8] = {};
    int i = b0;
    for (; i + 1 < b1; i += 2) {
        int s0 = srcS[i], s1 = srcS[i + 1];
        float w0 = wS[i], w1 = wS[i + 1];
        bf16x8 v0 = *(const bf16x8*)&Abf[(size_t)s0 * 128 + sub * 8];
        bf16x8 v1 = *(const bf16x8*)&Abf[(size_t)s1 * 128 + sub * 8];
        #pragma unroll
        for (int j = 0; j < 8; ++j)
            acc[j] += w0 * bf2f((unsigned short)v0[j]) + w1 * bf2f((unsigned short)v1[j]);
    }
    if (i < b1) {
        int s0 = srcS[i];
        float w0 = wS[i];
        bf16x8 v0 = *(const bf16x8*)&Abf[(size_t)s0 * 128 + sub * 8];
        #pragma unroll
        for (int j = 0; j < 8; ++j)
            acc[j] += w0 * bf2f((unsigned short)v0[j]);
    }
    bf16x8 o;
    #pragma unroll
    for (int j = 0; j < 8; ++j) o[j] = (short)f2bf(acc[j]);
    *(bf16x8*)&Abf[(size_t)node * 128 + 64 + sub * 8] = o;
}

// agg2y: per node (16 lanes): v = relu(x1p + segsum(w*hw1b) + c2b);
// xs = v + r1 (in-place over r1b); z = v + r2 (in-place over r2b);
// fused conv3 dots: out[node] = dot(xs,c3w0)+c3b ; y1[node] = dot(xs,c3w1).
__global__ __launch_bounds__(256) void k_agg2y(const unsigned short* __restrict__ hw1b,
                                               const int* __restrict__ srcS,
                                               const float* __restrict__ wS,
                                               const int* __restrict__ offs,
                                               const int* __restrict__ cnt,
                                               const float* __restrict__ c2b,
                                               const unsigned short* __restrict__ x1pb,
                                               unsigned short* __restrict__ rx1,   // r1b -> xsb
                                               unsigned short* __restrict__ rx2,   // r2b -> zb
                                               const float* __restrict__ c3w0,
                                               const float* __restrict__ c3w1,
                                               const float* __restrict__ c3b,
                                               float* __restrict__ out,
                                               float* __restrict__ y1,
                                               int N) {
    int node = blockIdx.x * 16 + (threadIdx.x >> 4);
    int k = threadIdx.x & 15;
    bool live = node < N;
    float acc[8] = {};
    int b0 = 0, b1 = 0;
    if (live) { b0 = offs[node]; b1 = b0 + cnt[node]; }
    int i = b0;
    for (; i + 1 < b1; i += 2) {
        int s0 = srcS[i], s1 = srcS[i + 1];
        float w0 = wS[i], w1 = wS[i + 1];
        bf16x8 v0 = *(const bf16x8*)&hw1b[(size_t)s0 * 128 + k * 8];
        bf16x8 v1 = *(const bf16x8*)&hw1b[(size_t)s1 * 128 + k * 8];
        #pragma unroll
        for (int j = 0; j < 8; ++j)
            acc[j] += w0 * bf2f((unsigned short)v0[j]) + w1 * bf2f((unsigned short)v1[j]);
    }
    if (i < b1) {
        int s0 = srcS[i];
        float w0 = wS[i];
        bf16x8 v0 = *(const bf16x8*)&hw1b[(size_t)s0 * 128 + k * 8];
        #pragma unroll
        for (int j = 0; j < 8; ++j)
            acc[j] += w0 * bf2f((unsigned short)v0[j]);
    }

    float a0 = 0.f, a1 = 0.f;
    if (live) {
        size_t base = (size_t)node * 128 + k * 8;
        bf16x8 x1v = *(const bf16x8*)&x1pb[base];
        bf16x8 r1v = *(const bf16x8*)&rx1[base];
        bf16x8 r2v = *(const bf16x8*)&rx2[base];
        bf16x8 xo, zo;
        int f0 = k * 8;
        #pragma unroll
        for (int j = 0; j < 8; ++j) {
            int f = f0 + j;
            float bias = (f < H2) ? c2b[f] : 0.f;
            float v = fmaxf(bf2f((unsigned short)x1v[j]) + acc[j] + bias, 0.f);
            float xsf = v + bf2f((unsigned short)r1v[j]);
            float zf  = v + bf2f((unsigned short)r2v[j]);
            xo[j] = (short)f2bf(xsf);
            zo[j] = (short)f2bf(zf);
            if (f < H2) {
                a0 += xsf * c3w0[f];
                a1 += xsf * c3w1[f];
            }
        }
        *(bf16x8*)&rx1[base] = xo;
        *(bf16x8*)&rx2[base] = zo;
    }
    #pragma unroll
    for (int off = 8; off; off >>= 1) {
        a0 += __shfl_xor(a0, off);
        a1 += __shfl_xor(a1, off);
    }
    if (live && k == 0) {
        out[node] = a0 + c3b[0];
        y1[node]  = a1;
    }
}

// per node: out[node] += sum w*y1[src]
__global__ void k_agg3(const float* __restrict__ y1, const int* __restrict__ srcS,
                       const float* __restrict__ wS, const int* __restrict__ offs,
                       const int* __restrict__ cnt, float* __restrict__ out, int N) {
    int node = blockIdx.x * 256 + threadIdx.x;
    if (node >= N) return;
    int b0 = offs[node], b1 = b0 + cnt[node];
    float a = 0.f;
    for (int i = b0; i < b1; ++i) a += wS[i] * y1[srcS[i]];
    out[node] += a;
}

// ---------------- weight packs ----------------

// Bt1X [640][128]: j<300 -> [c1w0|c1w1] ; 384<=j<484 -> l1w ; 512<=j<612 -> l2w ; else 0
__global__ void k_packB1X(const float* __restrict__ w0, const float* __restrict__ w1,
                          const float* __restrict__ lw1, const float* __restrict__ lw2,
                          unsigned short* __restrict__ Bt) {
    int i = blockIdx.x * 256 + threadIdx.x;    // 640*128
    if (i >= 640 * 128) return;
    int j = i >> 7, k = i & 127;
    float v = 0.f;
    if (j < H1) {
        if (k < DIN) v = w0[(size_t)k * H1 + j];
        else if (k >= 64 && k < 64 + DIN) v = w1[(size_t)(k - 64) * H1 + j];
    } else if (j >= 384 && j < 384 + H2) {
        if (k < DIN) v = lw1[(size_t)k * H2 + (j - 384)];
    } else if (j >= 512 && j < 512 + H2) {
        if (k < DIN) v = lw2[(size_t)k * H2 + (j - 512)];
    }
    Bt[i] = f2bf(v);
}

// Bt2X [256][320]: j<100 -> c2w0 col j ; 128<=j<228 -> c2w1 col (j-128) ; else 0
__global__ void k_packB2X(const float* __restrict__ w0, const float* __restrict__ w1,
                          unsigned short* __restrict__ Bt) {
    int i = blockIdx.x * 256 + threadIdx.x;    // 256*320
    if (i >= 256 * 320) return;
    int j = i / 320, k = i % 320;
    float v = 0.f;
    if (k < H1) {
        if (j < H2) v = w0[(size_t)k * H2 + j];
        else if (j >= 128 && j < 128 + H2) v = w1[(size_t)k * H2 + (j - 128)];
    }
    Bt[i] = f2bf(v);
}

// ---------------- fused conv1(+lin)+conv2 MFMA ----------------
// Phase 1: A[row0..row0+128][128] @ Bt1X[640][128] -> h (LDS, XOR-swizzled) + r1p/r2p.
// Phase 2: h(LDS)[128][320] @ Bt2X[256][320] -> x1p / hwp.
// Swapped-operand MFMA throughout (row = lane&15, col quad = (lane>>4)*4).
// LDS h element index: r*320 + (c ^ ((r&7)<<3))  -> 2-way bank conflicts only.

__global__ __launch_bounds__(256) void gemm_fused(
    const unsigned short* __restrict__ A,     // Abf [N][128]
    const unsigned short* __restrict__ Bt1,   // [640][128]
    const unsigned short* __restrict__ Bt2,   // [256][320]
    const float* __restrict__ c1b, const float* __restrict__ l1b,
    const float* __restrict__ l2b,
    unsigned short* __restrict__ r1p, unsigned short* __restrict__ r2p,
    unsigned short* __restrict__ x1p, unsigned short* __restrict__ hwp,
    int M)
{
    extern __shared__ unsigned short hL[];    // 128*320 shorts = 80KB
    const int tid = threadIdx.x;
    const int wave = tid >> 6, lane = tid & 63;
    const int wr = wave >> 1, wc = wave & 1;
    const int row0 = blockIdx.x * 128;
    const int kofs = (lane >> 4) * 8;
    const int arow = wr * 64 + (lane & 15);

    // ---- phase 1: conv1 + lin over 5 col-chunks ----
    for (int cc = 0; cc < 5; ++cc) {
        int col0 = cc * 128;
        int bcol = col0 + wc * 64 + (lane & 15);
        f32x4 acc[4][4] = {};
        #pragma unroll
        for (int ks = 0; ks < 4; ++ks) {
            bf16x8 af[4], bg[4];
            #pragma unroll
            for (int n = 0; n < 4; ++n)
                bg[n] = *(const bf16x8*)(Bt1 + (size_t)(bcol + n * 16) * 128 + ks * 32 + kofs);
            #pragma unroll
            for (int m = 0; m < 4; ++m)
                af[m] = *(const bf16x8*)(A + (size_t)(row0 + arow + m * 16) * 128 + ks * 32 + kofs);
            #pragma unroll
            for (int m = 0; m < 4; ++m)
                #pragma unroll
                for (int n = 0; n < 4; ++n)
                    acc[m][n] = __builtin_amdgcn_mfma_f32_16x16x32_bf16(bg[n], af[m], acc[m][n], 0, 0, 0);
        }
        #pragma unroll
        for (int m = 0; m < 4; ++m) {
            int rloc = wr * 64 + m * 16 + (lane & 15);
            int row = row0 + rloc;
            bool rlive = row < M;
            #pragma unroll
            for (int n = 0; n < 4; ++n) {
                int col = col0 + wc * 64 + n * 16 + (lane >> 4) * 4;
                bf16x4 o;
                if (col < 320) {
                    #pragma unroll
                    for (int i = 0; i < 4; ++i) {
                        int c = col + i;
                        float ov = (c < H1 && rlive) ? fmaxf(acc[m][n][i] + c1b[c], 0.f) : 0.f;
                        o[i] = (short)f2bf(ov);
                    }
                    *(bf16x4*)&hL[rloc * 320 + (col ^ ((rloc & 7) << 3))] = o;
                } else if (col >= 384 && col < 512) {
                    if (rlive) {
                        int c0 = col - 384;
                        #pragma unroll
                        for (int i = 0; i < 4; ++i) {
                            int c = c0 + i;
                            float ov = (c < H2) ? fmaxf(acc[m][n][i] + l1b[c], 0.f) : 0.f;
                            o[i] = (short)f2bf(ov);
                        }
                        *(bf16x4*)&r1p[(size_t)row * 128 + c0] = o;
                    }
                } else if (col >= 512) {
                    if (rlive) {
                        int c0 = col - 512;
                        #pragma unroll
                        for (int i = 0; i < 4; ++i) {
                            int c = c0 + i;
                            float ov = (c < H2) ? fmaxf(acc[m][n][i] + l2b[c], 0.f) : 0.f;
                            o[i] = (short)f2bf(ov);
                        }
                        *(bf16x4*)&r2p[(size_t)row * 128 + c0] = o;
                    }
                }
            }
        }
    }
    __syncthreads();

    // ---- phase 2: conv2 over 2 col-chunks, K=320 from LDS ----
    for (int cc = 0; cc < 2; ++cc) {
        int col0 = cc * 128;
        int bcol = col0 + wc * 64 + (lane & 15);
        f32x4 acc[4][4] = {};
        for (int ks = 0; ks < 10; ++ks) {
            bf16x8 af[4], bg[4];
            #pragma unroll
            for (int n = 0; n < 4; ++n)
                bg[n] = *(const bf16x8*)(Bt2 + (size_t)(bcol + n * 16) * 320 + ks * 32 + kofs);
            #pragma unroll
            for (int m = 0; m < 4; ++m) {
                int r = arow + m * 16;
                af[m] = *(const bf16x8*)&hL[r * 320 + ((ks * 32 + kofs) ^ ((r & 7) << 3))];
            }
            #pragma unroll
            for (int m = 0; m < 4; ++m)
                #pragma unroll
                for (int n = 0; n < 4; ++n)
                    acc[m][n] = __builtin_amdgcn_mfma_f32_16x16x32_bf16(bg[n], af[m], acc[m][n], 0, 0, 0);
        }
        #pragma unroll
        for (int m = 0; m < 4; ++m) {
            int row = row0 + wr * 64 + m * 16 + (lane & 15);
            if (row >= M) continue;
            #pragma unroll
            for (int n = 0; n < 4; ++n) {
                int col = col0 + wc * 64 + n * 16 + (lane >> 4) * 4;
                bf16x4 o;
                if (col < 128) {
                    #pragma unroll
                    for (int i = 0; i < 4; ++i) {
                        int c = col + i;
                        o[i] = (short)((c < H2) ? f2bf(acc[m][n][i]) : (unsigned short)0);
                    }
                    *(bf16x4*)&x1p[(size_t)row * 128 + col] = o;
                } else {
                    int c0 = col - 128;   // matches Bt2X: c2w1 at rows 128..227
                    #pragma unroll
                    for (int i = 0; i < 4; ++i) {
                        int c = c0 + i;
                        o[i] = (short)((c < H2) ? f2bf(acc[m][n][i]) : (unsigned short)0);
                    }
                    *(bf16x4*)&hwp[(size_t)row * 128 + c0] = o;
                }
            }
        }
    }
}

// ---------------- combined loss: grid-stride, per-block partials ----------------

__global__ __launch_bounds__(256) void k_loss2(const unsigned short* __restrict__ zb,
                                               const int* __restrict__ ei,
                                               const int* __restrict__ nei,
                                               int E, int En,
                                               float* __restrict__ part) {
    __shared__ float shP[4], shN[4];
    int k = threadIdx.x & 15;
    int grp = (blockIdx.x * 256 + threadIdx.x) >> 4;
    int ngrp = (gridDim.x * 256) >> 4;
    int tot = E + En;
    float sumP = 0.f, sumN = 0.f;

    for (int edge = grp; edge < tot; edge += ngrp) {
        int a, b;
        bool pos = edge < E;
        if (pos) { a = ei[edge]; b = ei[E + edge]; }
        else     { int e2 = edge - E; a = nei[e2]; b = nei[En + e2]; }
        bf16x8 va = *(const bf16x8*)&zb[(size_t)a * 128 + k * 8];
        bf16x8 vb = *(const bf16x8*)&zb[(size_t)b * 128 + k * 8];
        float d = 0.f;
        #pragma unroll
        for (int j = 0; j < 8; ++j)
            d += bf2f((unsigned short)va[j]) * bf2f((unsigned short)vb[j]);
        #pragma unroll
        for (int off = 8; off; off >>= 1) d += __shfl_xor(d, off);
        if (k == 0) {
            float s = 1.f / (1.f + expf(-d));
            if (pos) sumP += -logf(s + 1e-15f);
            else     sumN += -logf(1.f - s + 1e-15f);
        }
    }

    #pragma unroll
    for (int off = 32; off; off >>= 1) {
        sumP += __shfl_xor(sumP, off);
        sumN += __shfl_xor(sumN, off);
    }
    int wid = threadIdx.x >> 6;
    if ((threadIdx.x & 63) == 0) { shP[wid] = sumP; shN[wid] = sumN; }
    __syncthreads();
    if (threadIdx.x == 0)
        part[blockIdx.x * 2 + 0] = shP[0] + shP[1] + shP[2] + shP[3];
    if (threadIdx.x == 1)
        part[blockIdx.x * 2 + 1] = shN[0] + shN[1] + shN[2] + shN[3];
}

__global__ __launch_bounds__(256) void k_final2(const float* __restrict__ part, int nb,
                                                const float* __restrict__ c1,
                                                const float* __restrict__ c2,
                                                float* __restrict__ out, int N,
                                                float invEp, float invEn) {
    __shared__ float sp[4], sn[4];
    float aP = 0.f, aN = 0.f;
    for (int i = threadIdx.x; i < nb; i += 256) {
        aP += part[2 * i + 0];
        aN += part[2 * i + 1];
    }
    #pragma unroll
    for (int off = 32; off; off >>= 1) {
        aP += __shfl_xor(aP, off);
        aN += __shfl_xor(aN, off);
    }
    int wid = threadIdx.x >> 6;
    if ((threadIdx.x & 63) == 0) { sp[wid] = aP; sn[wid] = aN; }
    __syncthreads();
    if (threadIdx.x == 0) {
        float P = sp[0] + sp[1] + sp[2] + sp[3];
        float Nn = sn[0] + sn[1] + sn[2] + sn[3];
        out[N]     = P * invEp + Nn * invEn;
        out[N + 1] = c1[0];
        out[N + 2] = c2[0];
    }
}

// ---------------- launch ----------------

extern "C" void kernel_launch(void* const* d_in, const int* in_sizes, int n_in,
                              void* d_out, int out_size, void* d_ws, size_t ws_size,
                              hipStream_t stream) {
    const float* x   = (const float*)d_in[0];
    const int*   ei  = (const int*)d_in[1];
    const int*   nei = (const int*)d_in[2];
    const float* c1w0 = (const float*)d_in[3];
    const float* c1w1 = (const float*)d_in[4];
    const float* c1b  = (const float*)d_in[5];
    const float* c2w0 = (const float*)d_in[6];
    const float* c2w1 = (const float*)d_in[7];
    const float* c2b  = (const float*)d_in[8];
    const float* c3w0 = (const float*)d_in[9];
    const float* c3w1 = (const float*)d_in[10];
    const float* c3b  = (const float*)d_in[11];
    const float* l1w  = (const float*)d_in[12];
    const float* l1b  = (const float*)d_in[13];
    const float* l2w  = (const float*)d_in[14];
    const float* l2b  = (const float*)d_in[15];
    const float* c1s  = (const float*)d_in[16];
    const float* c2s  = (const float*)d_in[17];

    const int N  = in_sizes[0] / DIN;      // 100000
    const int E  = in_sizes[1] / 2;        // 262144
    const int En = in_sizes[2] / 2;        // 262144

    const int* row = ei;        // src
    const int* col = ei + E;    // dst

    // ---- workspace layout (peak ~131 MiB) ----
    char* ws = (char*)d_ws;
    const size_t MB = 1024ull * 1024ull;
    const size_t KB = 1024ull;
    int*   srcS  = (int*)  (ws + 1 * MB);               // E i32 (1MiB)
    float* wS    = (float*)(ws + 2 * MB);               // E f32 (1MiB)
    int*   cnt   = (int*)  (ws + 3 * MB);               // N i32
    int*   offs  = (int*)  (ws + 3 * MB + 512 * KB);    // N i32
    int*   cur   = (int*)  (ws + 4 * MB);               // N i32
    float* y1    = (float*)(ws + 5 * MB);               // N f32 (0.4MiB)
    int*   bsum  = (int*)  (ws + 5 * MB + 416 * KB);    // 256 i32
    float* part  = (float*)(ws + 5 * MB + 420 * KB);    // 2048*2 f32 (16KB)
    unsigned short* Bt1X = (unsigned short*)(ws + 5 * MB + 448 * KB); // 640*128*2=160KB
    unsigned short* Bt2  = (unsigned short*)(ws + 5 * MB + 640 * KB); // 256*320*2=160KB
    unsigned short* Abf  = (unsigned short*)(ws + 6 * MB);    // N*128 bf16 (24.4MiB)
    unsigned short* r1b  = (unsigned short*)(ws + 31 * MB);   // N*128 bf16 -> xsb
    unsigned short* r2b  = (unsigned short*)(ws + 56 * MB);   // N*128 bf16 -> zb
    unsigned short* x1pb = (unsigned short*)(ws + 81 * MB);   // N*128 bf16
    unsigned short* hw1b = (unsigned short*)(ws + 106 * MB);  // N*128 bf16 -> 130.4

    const int ZG = 1024;
    int gE = (E + 255) / 256;
    int gN = (N + 255) / 256;
    int NB = (N + 1023) / 1024;            // 98 <= 256

    // ---- degree histogram ----
    k_zero<<<ZG, 256, 0, stream>>>((float*)cnt, N);
    k_hist<<<gE, 256, 0, stream>>>(col, cnt, E);

    // ---- CSR build: scan (also seeds cur) + reorder-with-inline-weights ----
    k_scan1<<<NB, 256, 0, stream>>>(cnt, offs, bsum, N);
    k_scan2<<<1, 256, 0, stream>>>(bsum, NB);
    k_scan3<<<gN, 256, 0, stream>>>(offs, bsum, cur, N);
    k_reorder2<<<gE, 256, 0, stream>>>(row, col, cnt, cur, srcS, wS, E);

    // ---- weight packs (tiny) ----
    k_packB1X<<<(640 * 128 + 255) / 256, 256, 0, stream>>>(c1w0, c1w1, l1w, l2w, Bt1X);
    k_packB2X<<<(256 * 320 + 255) / 256, 256, 0, stream>>>(c2w0, c2w1, Bt2);

    // ---- x -> Abf x-half (bf16), then t1-half via bf16 CSR gather ----
    k_cvtX<<<(N * 8 + 255) / 256, 256, 0, stream>>>(x, Abf, N);
    k_agg1b<<<(N + 31) / 32, 256, 0, stream>>>(srcS, wS, offs, cnt, Abf, N);

    // ---- fused conv1(+lin)+conv2 MFMA, h lives in LDS only ----
    {
        int grid = (N + 127) / 128;
        gemm_fused<<<grid, 256, 128 * 320 * sizeof(unsigned short), stream>>>(
            Abf, Bt1X, Bt2, c1b, l1b, l2b, r1b, r2b, x1pb, hw1b, N);
    }

    // ---- fused conv2-aggregate + bias/relu + xs/z + conv3 dots ----
    k_agg2y<<<(N + 15) / 16, 256, 0, stream>>>(hw1b, srcS, wS, offs, cnt, c2b,
                                               x1pb, r1b, r2b,
                                               c3w0, c3w1, c3b, (float*)d_out, y1, N);

    // ---- conv3 aggregate: out[node] += segsum(w * y1[src]) ----
    k_agg3<<<gN, 256, 0, stream>>>(y1, srcS, wS, offs, cnt, (float*)d_out, N);

    // ---- combined loss: grid-stride, no same-address atomics ----
    const int LB = 2048;
    k_loss2<<<LB, 256, 0, stream>>>(r2b, ei, nei, E, En, part);
    k_final2<<<1, 256, 0, stream>>>(part, LB, c1s, c2s, (float*)d_out, N,
                                    1.0f / E, 1.0f / En);
}

// Round 16
// 327.551 us; speedup vs baseline: 1.2651x; 1.2651x over previous
//
#include <hip/hip_runtime.h>
#include <hip/hip_bf16.h>
#include <cstddef>

#define DIN 58
#define H1  300
#define H2  100

using bf16x8 = __attribute__((ext_vector_type(8))) short;
using f32x4  = __attribute__((ext_vector_type(4))) float;

__device__ inline unsigned short f2bf(float f) {
    union { float f; unsigned int u; } v; v.f = f;
    unsigned int r = v.u + 0x7fff + ((v.u >> 16) & 1);   // RNE
    return (unsigned short)(r >> 16);
}
__device__ inline float bf2f(unsigned short h) {
    union { unsigned int u; float f; } v; v.u = ((unsigned int)h) << 16;
    return v.f;
}

// ---------------- utility ----------------

__global__ void k_zero(float* __restrict__ p, long n) {
    long i = (long)blockIdx.x * 256 + threadIdx.x;
    long stride = (long)gridDim.x * 256;
    for (; i < n; i += stride) p[i] = 0.f;
}

// ---------------- degree / CSR ----------------

__global__ void k_hist(const int* __restrict__ dst, int* __restrict__ cnt, int E) {
    int e = blockIdx.x * 256 + threadIdx.x;
    if (e < E) atomicAdd(&cnt[dst[e]], 1);
}

// block scan: 1024 items/block (256 thr x 4)
__global__ __launch_bounds__(256) void k_scan1(const int* __restrict__ cnt,
                                               int* __restrict__ offs,
                                               int* __restrict__ bsum, int N) {
    __shared__ int ts[256];
    int b = blockIdx.x, t = threadIdx.x;
    int base = b * 1024 + t * 4;
    int v0 = (base + 0 < N) ? cnt[base + 0] : 0;
    int v1 = (base + 1 < N) ? cnt[base + 1] : 0;
    int v2 = (base + 2 < N) ? cnt[base + 2] : 0;
    int v3 = (base + 3 < N) ? cnt[base + 3] : 0;
    ts[t] = v0 + v1 + v2 + v3;
    __syncthreads();
    for (int off = 1; off < 256; off <<= 1) {
        int u = (t >= off) ? ts[t - off] : 0;
        __syncthreads();
        ts[t] += u;
        __syncthreads();
    }
    int ex = (t > 0) ? ts[t - 1] : 0;
    if (base + 0 < N) offs[base + 0] = ex;
    if (base + 1 < N) offs[base + 1] = ex + v0;
    if (base + 2 < N) offs[base + 2] = ex + v0 + v1;
    if (base + 3 < N) offs[base + 3] = ex + v0 + v1 + v2;
    if (t == 255) bsum[b] = ts[255];
}

__global__ __launch_bounds__(256) void k_scan2(int* __restrict__ bsum, int nb) {
    __shared__ int ts[256];
    int t = threadIdx.x;
    ts[t] = (t < nb) ? bsum[t] : 0;
    __syncthreads();
    for (int off = 1; off < 256; off <<= 1) {
        int u = (t >= off) ? ts[t - off] : 0;
        __syncthreads();
        ts[t] += u;
        __syncthreads();
    }
    if (t < nb) bsum[t] = (t > 0) ? ts[t - 1] : 0;
}

// also seeds cur = offs (for reorder's atomic cursor)
__global__ void k_scan3(int* __restrict__ offs, const int* __restrict__ bsum,
                        int* __restrict__ cur, int N) {
    int i = blockIdx.x * 256 + threadIdx.x;
    if (i < N) {
        int v = offs[i] + bsum[i >> 10];
        offs[i] = v;
        cur[i] = v;
    }
}

// reorder with inline weight: w = -rsqrt(deg[src]) * rsqrt(deg[dst])
__global__ void k_reorder2(const int* __restrict__ row, const int* __restrict__ col,
                           const int* __restrict__ cnt,
                           int* __restrict__ cur, int* __restrict__ srcS,
                           float* __restrict__ wS, int E) {
    int e = blockIdx.x * 256 + threadIdx.x;
    if (e < E) {
        int s = row[e], d = col[e];
        int p = atomicAdd(&cur[d], 1);
        float ds = (float)max(cnt[s], 1);
        float dd = (float)max(cnt[d], 1);
        srcS[p] = s;
        wS[p] = -rsqrtf(ds) * rsqrtf(dd);
    }
}

// ---------------- x -> Abf x-half (bf16 streaming convert) ----------------

__global__ void k_cvtX(const float* __restrict__ x, unsigned short* __restrict__ Abf,
                       int N) {
    int t = blockIdx.x * 256 + threadIdx.x;      // node*8 + sub
    int node = t >> 3, sub = t & 7;
    if (node >= N) return;
    bf16x8 o;
    #pragma unroll
    for (int j = 0; j < 8; ++j) {
        int c = sub * 8 + j;
        float v = (c < DIN) ? x[(size_t)node * DIN + c] : 0.f;
        o[j] = (short)f2bf(v);
    }
    *(bf16x8*)&Abf[(size_t)node * 128 + sub * 8] = o;
}

// ---------------- CSR segmented reductions ----------------

// agg1b: 8 lanes/node, gather bf16 x-half rows of Abf, write t1-half of Abf.
__global__ __launch_bounds__(256) void k_agg1b(const int* __restrict__ srcS,
                                               const float* __restrict__ wS,
                                               const int* __restrict__ offs,
                                               const int* __restrict__ cnt,
                                               unsigned short* __restrict__ Abf, int N) {
    int node = blockIdx.x * 32 + (threadIdx.x >> 3);
    int sub = threadIdx.x & 7;
    if (node >= N) return;
    int b0 = offs[node], b1 = b0 + cnt[node];
    float acc[8] = {};
    int i = b0;
    for (; i + 1 < b1; i += 2) {
        int s0 = srcS[i], s1 = srcS[i + 1];
        float w0 = wS[i], w1 = wS[i + 1];
        bf16x8 v0 = *(const bf16x8*)&Abf[(size_t)s0 * 128 + sub * 8];
        bf16x8 v1 = *(const bf16x8*)&Abf[(size_t)s1 * 128 + sub * 8];
        #pragma unroll
        for (int j = 0; j < 8; ++j)
            acc[j] += w0 * bf2f((unsigned short)v0[j]) + w1 * bf2f((unsigned short)v1[j]);
    }
    if (i < b1) {
        int s0 = srcS[i];
        float w0 = wS[i];
        bf16x8 v0 = *(const bf16x8*)&Abf[(size_t)s0 * 128 + sub * 8];
        #pragma unroll
        for (int j = 0; j < 8; ++j)
            acc[j] += w0 * bf2f((unsigned short)v0[j]);
    }
    bf16x8 o;
    #pragma unroll
    for (int j = 0; j < 8; ++j) o[j] = (short)f2bf(acc[j]);
    *(bf16x8*)&Abf[(size_t)node * 128 + 64 + sub * 8] = o;
}

// agg2y: per node (16 lanes): v = relu(x1p + segsum(w*hw1b) + c2b);
// xs = v + r1 (in-place over r1b); z = v + r2 (in-place over r2b);
// fused conv3 dots: out[node] = dot(xs,c3w0)+c3b ; y1[node] = dot(xs,c3w1).
__global__ __launch_bounds__(256) void k_agg2y(const unsigned short* __restrict__ hw1b,
                                               const int* __restrict__ srcS,
                                               const float* __restrict__ wS,
                                               const int* __restrict__ offs,
                                               const int* __restrict__ cnt,
                                               const float* __restrict__ c2b,
                                               const unsigned short* __restrict__ x1pb,
                                               unsigned short* __restrict__ rx1,   // r1b -> xsb
                                               unsigned short* __restrict__ rx2,   // r2b -> zb
                                               const float* __restrict__ c3w0,
                                               const float* __restrict__ c3w1,
                                               const float* __restrict__ c3b,
                                               float* __restrict__ out,
                                               float* __restrict__ y1,
                                               int N) {
    int node = blockIdx.x * 16 + (threadIdx.x >> 4);
    int k = threadIdx.x & 15;
    bool live = node < N;
    float acc[8] = {};
    int b0 = 0, b1 = 0;
    if (live) { b0 = offs[node]; b1 = b0 + cnt[node]; }
    int i = b0;
    for (; i + 1 < b1; i += 2) {
        int s0 = srcS[i], s1 = srcS[i + 1];
        float w0 = wS[i], w1 = wS[i + 1];
        bf16x8 v0 = *(const bf16x8*)&hw1b[(size_t)s0 * 128 + k * 8];
        bf16x8 v1 = *(const bf16x8*)&hw1b[(size_t)s1 * 128 + k * 8];
        #pragma unroll
        for (int j = 0; j < 8; ++j)
            acc[j] += w0 * bf2f((unsigned short)v0[j]) + w1 * bf2f((unsigned short)v1[j]);
    }
    if (i < b1) {
        int s0 = srcS[i];
        float w0 = wS[i];
        bf16x8 v0 = *(const bf16x8*)&hw1b[(size_t)s0 * 128 + k * 8];
        #pragma unroll
        for (int j = 0; j < 8; ++j)
            acc[j] += w0 * bf2f((unsigned short)v0[j]);
    }

    float a0 = 0.f, a1 = 0.f;
    if (live) {
        size_t base = (size_t)node * 128 + k * 8;
        bf16x8 x1v = *(const bf16x8*)&x1pb[base];
        bf16x8 r1v = *(const bf16x8*)&rx1[base];
        bf16x8 r2v = *(const bf16x8*)&rx2[base];
        bf16x8 xo, zo;
        int f0 = k * 8;
        #pragma unroll
        for (int j = 0; j < 8; ++j) {
            int f = f0 + j;
            float bias = (f < H2) ? c2b[f] : 0.f;
            float v = fmaxf(bf2f((unsigned short)x1v[j]) + acc[j] + bias, 0.f);
            float xsf = v + bf2f((unsigned short)r1v[j]);
            float zf  = v + bf2f((unsigned short)r2v[j]);
            xo[j] = (short)f2bf(xsf);
            zo[j] = (short)f2bf(zf);
            if (f < H2) {
                a0 += xsf * c3w0[f];
                a1 += xsf * c3w1[f];
            }
        }
        *(bf16x8*)&rx1[base] = xo;
        *(bf16x8*)&rx2[base] = zo;
    }
    // reduce across the 16 lanes of this node group (xor masks < 16 stay in-group)
    #pragma unroll
    for (int off = 8; off; off >>= 1) {
        a0 += __shfl_xor(a0, off);
        a1 += __shfl_xor(a1, off);
    }
    if (live && k == 0) {
        out[node] = a0 + c3b[0];
        y1[node]  = a1;
    }
}

// per node: out[node] += sum w*y1[src]
__global__ void k_agg3(const float* __restrict__ y1, const int* __restrict__ srcS,
                       const float* __restrict__ wS, const int* __restrict__ offs,
                       const int* __restrict__ cnt, float* __restrict__ out, int N) {
    int node = blockIdx.x * 256 + threadIdx.x;
    if (node >= N) return;
    int b0 = offs[node], b1 = b0 + cnt[node];
    float a = 0.f;
    for (int i = b0; i < b1; ++i) a += wS[i] * y1[srcS[i]];
    out[node] += a;
}

// ---------------- weight packs ----------------

// Bt1X [640][128]: j<300 -> [c1w0|c1w1] ; 384<=j<484 -> l1w ; 512<=j<612 -> l2w ; else 0
__global__ void k_packB1X(const float* __restrict__ w0, const float* __restrict__ w1,
                          const float* __restrict__ lw1, const float* __restrict__ lw2,
                          unsigned short* __restrict__ Bt) {
    int i = blockIdx.x * 256 + threadIdx.x;    // 640*128
    if (i >= 640 * 128) return;
    int j = i >> 7, k = i & 127;
    float v = 0.f;
    if (j < H1) {
        if (k < DIN) v = w0[(size_t)k * H1 + j];
        else if (k >= 64 && k < 64 + DIN) v = w1[(size_t)(k - 64) * H1 + j];
    } else if (j >= 384 && j < 384 + H2) {
        if (k < DIN) v = lw1[(size_t)k * H2 + (j - 384)];
    } else if (j >= 512 && j < 512 + H2) {
        if (k < DIN) v = lw2[(size_t)k * H2 + (j - 512)];
    }
    Bt[i] = f2bf(v);
}

// Bt2X [256][320]: j<100 -> c2w0 col j ; 128<=j<228 -> c2w1 col (j-128) ; else 0
__global__ void k_packB2X(const float* __restrict__ w0, const float* __restrict__ w1,
                          unsigned short* __restrict__ Bt) {
    int i = blockIdx.x * 256 + threadIdx.x;    // 256*320
    if (i >= 256 * 320) return;
    int j = i / 320, k = i % 320;
    float v = 0.f;
    if (k < H1) {
        if (j < H2) v = w0[(size_t)k * H2 + j];
        else if (j >= 128 && j < 128 + H2) v = w1[(size_t)k * H2 + (j - 128)];
    }
    Bt[i] = f2bf(v);
}

// ---------------- conv1+lin MFMA: A[M][128] @ Bt1X -> hC / r1b / r2b ----------------

__global__ __launch_bounds__(256) void gemm_c1(
    const unsigned short* __restrict__ A,
    const unsigned short* __restrict__ Bt,
    const float* __restrict__ c1b, const float* __restrict__ l1b,
    const float* __restrict__ l2b,
    unsigned short* __restrict__ hC,    // [M][320] chunk-relative
    unsigned short* __restrict__ r1p,   // already offset by r0*128
    unsigned short* __restrict__ r2p,
    int M)
{
    __shared__ unsigned short As[128][40];
    __shared__ unsigned short Bs[128][40];
    const int tid = threadIdx.x;
    const int wave = tid >> 6, lane = tid & 63;
    const int wr = wave >> 1, wc = wave & 1;
    const int row0 = blockIdx.x * 128;
    const int col0 = blockIdx.y * 128;
    const int tr = tid >> 1;
    const int tk = (tid & 1) * 16;

    f32x4 acc[4][4] = {};

    for (int ks = 0; ks < 4; ++ks) {
        int kt = ks * 32;
        {
            int grow = row0 + tr;
            bf16x8 v0 = {}, v1 = {};
            if (grow < M) {
                const unsigned short* p = A + (size_t)grow * 128 + kt + tk;
                v0 = *(const bf16x8*)p;
                v1 = *(const bf16x8*)(p + 8);
            }
            *(bf16x8*)&As[tr][tk]     = v0;
            *(bf16x8*)&As[tr][tk + 8] = v1;
        }
        {
            int gcol = col0 + tr;
            const unsigned short* p = Bt + (size_t)gcol * 128 + kt + tk;
            *(bf16x8*)&Bs[tr][tk]     = *(const bf16x8*)p;
            *(bf16x8*)&Bs[tr][tk + 8] = *(const bf16x8*)(p + 8);
        }
        __syncthreads();

        const int kofs = (lane >> 4) * 8;
        bf16x8 af[4], bg[4];
        const int arow = wr * 64 + (lane & 15);
        const int bcol = wc * 64 + (lane & 15);
        #pragma unroll
        for (int m = 0; m < 4; ++m) af[m] = *(const bf16x8*)&As[arow + m * 16][kofs];
        #pragma unroll
        for (int n = 0; n < 4; ++n) bg[n] = *(const bf16x8*)&Bs[bcol + n * 16][kofs];
        #pragma unroll
        for (int m = 0; m < 4; ++m)
            #pragma unroll
            for (int n = 0; n < 4; ++n)
                acc[m][n] = __builtin_amdgcn_mfma_f32_16x16x32_bf16(af[m], bg[n], acc[m][n], 0, 0, 0);
        __syncthreads();
    }

    #pragma unroll
    for (int m = 0; m < 4; ++m) {
        #pragma unroll
        for (int n = 0; n < 4; ++n) {
            int col = col0 + wc * 64 + n * 16 + (lane & 15);
            #pragma unroll
            for (int i = 0; i < 4; ++i) {
                int row = row0 + wr * 64 + m * 16 + (lane >> 4) * 4 + i;
                if (row >= M) continue;
                float v = acc[m][n][i];
                if (col < 320) {
                    float ov = 0.f;
                    if (col < H1) ov = fmaxf(v + c1b[col], 0.f);
                    hC[(size_t)row * 320 + col] = f2bf(ov);
                } else if (col >= 384 && col < 512) {
                    int c = col - 384;
                    float ov = (c < H2) ? fmaxf(v + l1b[c], 0.f) : 0.f;
                    r1p[(size_t)row * 128 + c] = f2bf(ov);
                } else if (col >= 512) {
                    int c = col - 512;
                    float ov = (c < H2) ? fmaxf(v + l2b[c], 0.f) : 0.f;
                    r2p[(size_t)row * 128 + c] = f2bf(ov);
                }
            }
        }
    }
}

// ---------------- conv2 MFMA: hC[M][320] @ Bt2X -> x1pb / hw1b (both [*][128] bf16) ----

__global__ __launch_bounds__(256) void gemm_c2(
    const unsigned short* __restrict__ A,     // hC chunk
    const unsigned short* __restrict__ Bt,    // [256][320]
    unsigned short* __restrict__ x1p,         // offset r0*128
    unsigned short* __restrict__ hwp,         // offset r0*128
    int M)
{
    __shared__ unsigned short As[128][40];
    __shared__ unsigned short Bs[128][40];
    const int tid = threadIdx.x;
    const int wave = tid >> 6, lane = tid & 63;
    const int wr = wave >> 1, wc = wave & 1;
    const int row0 = blockIdx.x * 128;
    const int col0 = blockIdx.y * 128;
    const int tr = tid >> 1;
    const int tk = (tid & 1) * 16;

    f32x4 acc[4][4] = {};

    for (int ks = 0; ks < 10; ++ks) {
        int kt = ks * 32;
        {
            int grow = row0 + tr;
            bf16x8 v0 = {}, v1 = {};
            if (grow < M) {
                const unsigned short* p = A + (size_t)grow * 320 + kt + tk;
                v0 = *(const bf16x8*)p;
                v1 = *(const bf16x8*)(p + 8);
            }
            *(bf16x8*)&As[tr][tk]     = v0;
            *(bf16x8*)&As[tr][tk + 8] = v1;
        }
        {
            int gcol = col0 + tr;
            const unsigned short* p = Bt + (size_t)gcol * 320 + kt + tk;
            *(bf16x8*)&Bs[tr][tk]     = *(const bf16x8*)p;
            *(bf16x8*)&Bs[tr][tk + 8] = *(const bf16x8*)(p + 8);
        }
        __syncthreads();

        const int kofs = (lane >> 4) * 8;
        bf16x8 af[4], bg[4];
        const int arow = wr * 64 + (lane & 15);
        const int bcol = wc * 64 + (lane & 15);
        #pragma unroll
        for (int m = 0; m < 4; ++m) af[m] = *(const bf16x8*)&As[arow + m * 16][kofs];
        #pragma unroll
        for (int n = 0; n < 4; ++n) bg[n] = *(const bf16x8*)&Bs[bcol + n * 16][kofs];
        #pragma unroll
        for (int m = 0; m < 4; ++m)
            #pragma unroll
            for (int n = 0; n < 4; ++n)
                acc[m][n] = __builtin_amdgcn_mfma_f32_16x16x32_bf16(af[m], bg[n], acc[m][n], 0, 0, 0);
        __syncthreads();
    }

    #pragma unroll
    for (int m = 0; m < 4; ++m) {
        #pragma unroll
        for (int n = 0; n < 4; ++n) {
            int col = col0 + wc * 64 + n * 16 + (lane & 15);
            #pragma unroll
            for (int i = 0; i < 4; ++i) {
                int row = row0 + wr * 64 + m * 16 + (lane >> 4) * 4 + i;
                if (row >= M) continue;
                float v = acc[m][n][i];
                if (col < 128) {
                    unsigned short o = (col < H2) ? f2bf(v) : (unsigned short)0;
                    x1p[(size_t)row * 128 + col] = o;
                } else {
                    int c = col - 128;   // matches Bt2X: c2w1 at rows 128..227
                    unsigned short o = (c < H2) ? f2bf(v) : (unsigned short)0;
                    hwp[(size_t)row * 128 + c] = o;
                }
            }
        }
    }
}

// ---------------- combined loss: grid-stride, per-block partials ----------------

__global__ __launch_bounds__(256) void k_loss2(const unsigned short* __restrict__ zb,
                                               const int* __restrict__ ei,
                                               const int* __restrict__ nei,
                                               int E, int En,
                                               float* __restrict__ part) {
    __shared__ float shP[4], shN[4];
    int k = threadIdx.x & 15;
    int grp = (blockIdx.x * 256 + threadIdx.x) >> 4;
    int ngrp = (gridDim.x * 256) >> 4;
    int tot = E + En;
    float sumP = 0.f, sumN = 0.f;

    for (int edge = grp; edge < tot; edge += ngrp) {
        int a, b;
        bool pos = edge < E;
        if (pos) { a = ei[edge]; b = ei[E + edge]; }
        else     { int e2 = edge - E; a = nei[e2]; b = nei[En + e2]; }
        bf16x8 va = *(const bf16x8*)&zb[(size_t)a * 128 + k * 8];
        bf16x8 vb = *(const bf16x8*)&zb[(size_t)b * 128 + k * 8];
        float d = 0.f;
        #pragma unroll
        for (int j = 0; j < 8; ++j)
            d += bf2f((unsigned short)va[j]) * bf2f((unsigned short)vb[j]);
        #pragma unroll
        for (int off = 8; off; off >>= 1) d += __shfl_xor(d, off);
        if (k == 0) {
            float s = 1.f / (1.f + expf(-d));
            if (pos) sumP += -logf(s + 1e-15f);
            else     sumN += -logf(1.f - s + 1e-15f);
        }
    }

    #pragma unroll
    for (int off = 32; off; off >>= 1) {
        sumP += __shfl_xor(sumP, off);
        sumN += __shfl_xor(sumN, off);
    }
    int wid = threadIdx.x >> 6;
    if ((threadIdx.x & 63) == 0) { shP[wid] = sumP; shN[wid] = sumN; }
    __syncthreads();
    if (threadIdx.x == 0)
        part[blockIdx.x * 2 + 0] = shP[0] + shP[1] + shP[2] + shP[3];
    if (threadIdx.x == 1)
        part[blockIdx.x * 2 + 1] = shN[0] + shN[1] + shN[2] + shN[3];
}

__global__ __launch_bounds__(256) void k_final2(const float* __restrict__ part, int nb,
                                                const float* __restrict__ c1,
                                                const float* __restrict__ c2,
                                                float* __restrict__ out, int N,
                                                float invEp, float invEn) {
    __shared__ float sp[4], sn[4];
    float aP = 0.f, aN = 0.f;
    for (int i = threadIdx.x; i < nb; i += 256) {
        aP += part[2 * i + 0];
        aN += part[2 * i + 1];
    }
    #pragma unroll
    for (int off = 32; off; off >>= 1) {
        aP += __shfl_xor(aP, off);
        aN += __shfl_xor(aN, off);
    }
    int wid = threadIdx.x >> 6;
    if ((threadIdx.x & 63) == 0) { sp[wid] = aP; sn[wid] = aN; }
    __syncthreads();
    if (threadIdx.x == 0) {
        float P = sp[0] + sp[1] + sp[2] + sp[3];
        float Nn = sn[0] + sn[1] + sn[2] + sn[3];
        out[N]     = P * invEp + Nn * invEn;
        out[N + 1] = c1[0];
        out[N + 2] = c2[0];
    }
}

// ---------------- launch ----------------

extern "C" void kernel_launch(void* const* d_in, const int* in_sizes, int n_in,
                              void* d_out, int out_size, void* d_ws, size_t ws_size,
                              hipStream_t stream) {
    const float* x   = (const float*)d_in[0];
    const int*   ei  = (const int*)d_in[1];
    const int*   nei = (const int*)d_in[2];
    const float* c1w0 = (const float*)d_in[3];
    const float* c1w1 = (const float*)d_in[4];
    const float* c1b  = (const float*)d_in[5];
    const float* c2w0 = (const float*)d_in[6];
    const float* c2w1 = (const float*)d_in[7];
    const float* c2b  = (const float*)d_in[8];
    const float* c3w0 = (const float*)d_in[9];
    const float* c3w1 = (const float*)d_in[10];
    const float* c3b  = (const float*)d_in[11];
    const float* l1w  = (const float*)d_in[12];
    const float* l1b  = (const float*)d_in[13];
    const float* l2w  = (const float*)d_in[14];
    const float* l2b  = (const float*)d_in[15];
    const float* c1s  = (const float*)d_in[16];
    const float* c2s  = (const float*)d_in[17];

    const int N  = in_sizes[0] / DIN;      // 100000
    const int E  = in_sizes[1] / 2;        // 262144
    const int En = in_sizes[2] / 2;        // 262144

    const int* row = ei;        // src
    const int* col = ei + E;    // dst

    // ---- workspace layout ----
    char* ws = (char*)d_ws;
    const size_t MB = 1024ull * 1024ull;
    const size_t KB = 1024ull;
    int*   srcS  = (int*)  (ws + 1 * MB);               // E i32 (1MiB)
    float* wS    = (float*)(ws + 2 * MB);               // E f32 (1MiB)
    int*   cnt   = (int*)  (ws + 3 * MB);               // N i32
    int*   offs  = (int*)  (ws + 3 * MB + 512 * KB);    // N i32
    int*   cur   = (int*)  (ws + 4 * MB);               // N i32
    float* y1    = (float*)(ws + 5 * MB);               // N f32 (0.4MiB)
    int*   bsum  = (int*)  (ws + 5 * MB + 416 * KB);    // 256 i32
    float* part  = (float*)(ws + 5 * MB + 420 * KB);    // 2048*2 f32 (16KB)
    unsigned short* Bt1X = (unsigned short*)(ws + 5 * MB + 448 * KB); // 640*128*2=160KB
    unsigned short* Bt2  = (unsigned short*)(ws + 5 * MB + 640 * KB); // 256*320*2=160KB
    unsigned short* Abf  = (unsigned short*)(ws + 6 * MB);    // N*128 bf16 (24.4MiB)
    unsigned short* r1b  = (unsigned short*)(ws + 31 * MB);   // N*128 bf16 -> xsb
    unsigned short* r2b  = (unsigned short*)(ws + 56 * MB);   // N*128 bf16 -> zb
    unsigned short* x1pb = (unsigned short*)(ws + 81 * MB);   // N*128 bf16
    unsigned short* hw1b = (unsigned short*)(ws + 106 * MB);  // N*128 bf16 -> 130.4
    unsigned short* hC   = (unsigned short*)(ws + 131 * MB);  // adaptive chunk [RC][320] bf16

    // adaptive GEMM chunk rows from actual workspace (deterministic)
    size_t hOff = 131 * MB;
    size_t avail = (ws_size > hOff + MB) ? (ws_size - hOff - MB) : 0;
    long maxRows = (long)(avail / 640);           // 320 cols * 2 B
    if (maxRows > N) maxRows = N;
    if (maxRows < 12500) maxRows = 12500;         // floor: 131+7.7 MiB, proven safe

    const int ZG = 1024;
    int gE = (E + 255) / 256;
    int gN = (N + 255) / 256;
    int NB = (N + 1023) / 1024;            // 98 <= 256

    // ---- degree histogram ----
    k_zero<<<ZG, 256, 0, stream>>>((float*)cnt, N);
    k_hist<<<gE, 256, 0, stream>>>(col, cnt, E);

    // ---- CSR build: scan (also seeds cur) + reorder-with-inline-weights ----
    k_scan1<<<NB, 256, 0, stream>>>(cnt, offs, bsum, N);
    k_scan2<<<1, 256, 0, stream>>>(bsum, NB);
    k_scan3<<<gN, 256, 0, stream>>>(offs, bsum, cur, N);
    k_reorder2<<<gE, 256, 0, stream>>>(row, col, cnt, cur, srcS, wS, E);

    // ---- weight packs (tiny) ----
    k_packB1X<<<(640 * 128 + 255) / 256, 256, 0, stream>>>(c1w0, c1w1, l1w, l2w, Bt1X);
    k_packB2X<<<(256 * 320 + 255) / 256, 256, 0, stream>>>(c2w0, c2w1, Bt2);

    // ---- x -> Abf x-half (bf16), then t1-half via bf16 CSR gather ----
    k_cvtX<<<(N * 8 + 255) / 256, 256, 0, stream>>>(x, Abf, N);
    k_agg1b<<<(N + 31) / 32, 256, 0, stream>>>(srcS, wS, offs, cnt, Abf, N);

    // ---- conv1(+lin) + conv2 MFMA, adaptive chunking (1 pass at ws>=192MiB) ----
    for (long r0 = 0; r0 < N; r0 += maxRows) {
        long rc = (N - r0 < maxRows) ? (N - r0) : maxRows;
        dim3 g1((rc + 127) / 128, 5);   // cols 0..639
        gemm_c1<<<g1, 256, 0, stream>>>(Abf + (size_t)r0 * 128, Bt1X,
                                        c1b, l1b, l2b,
                                        hC, r1b + (size_t)r0 * 128, r2b + (size_t)r0 * 128,
                                        (int)rc);
        dim3 g2((rc + 127) / 128, 2);   // cols 0..255
        gemm_c2<<<g2, 256, 0, stream>>>(hC, Bt2,
                                        x1pb + (size_t)r0 * 128, hw1b + (size_t)r0 * 128,
                                        (int)rc);
    }

    // ---- fused conv2-aggregate + bias/relu + xs/z + conv3 dots ----
    k_agg2y<<<(N + 15) / 16, 256, 0, stream>>>(hw1b, srcS, wS, offs, cnt, c2b,
                                               x1pb, r1b, r2b,
                                               c3w0, c3w1, c3b, (float*)d_out, y1, N);

    // ---- conv3 aggregate: out[node] += segsum(w * y1[src]) ----
    k_agg3<<<gN, 256, 0, stream>>>(y1, srcS, wS, offs, cnt, (float*)d_out, N);

    // ---- combined loss: grid-stride, no same-address atomics ----
    const int LB = 2048;
    k_loss2<<<LB, 256, 0, stream>>>(r2b, ei, nei, E, En, part);
    k_final2<<<1, 256, 0, stream>>>(part, LB, c1s, c2s, (float*)d_out, N,
                                    1.0f / E, 1.0f / En);
}

// Round 17
// 318.119 us; speedup vs baseline: 1.3026x; 1.0296x over previous
//
#include <hip/hip_runtime.h>
#include <hip/hip_bf16.h>
#include <cstddef>

#define DIN 58
#define H1  300
#define H2  100

using bf16x8 = __attribute__((ext_vector_type(8))) short;
using f32x4  = __attribute__((ext_vector_type(4))) float;

__device__ inline unsigned short f2bf(float f) {
    union { float f; unsigned int u; } v; v.f = f;
    unsigned int r = v.u + 0x7fff + ((v.u >> 16) & 1);   // RNE
    return (unsigned short)(r >> 16);
}
__device__ inline float bf2f(unsigned short h) {
    union { unsigned int u; float f; } v; v.u = ((unsigned int)h) << 16;
    return v.f;
}

// bijective XCD-aware block swizzle (m204): blocks sharing an A row-tile
// land on the SAME XCD so its private L2 serves the repeats.
__device__ inline void xcd_tile(int orig, int nwg, int nct, int& rowt, int& colt) {
    int q = nwg >> 3, r = nwg & 7;
    int xcd = orig & 7;
    int base = (xcd < r) ? xcd * (q + 1) : r * (q + 1) + (xcd - r) * q;
    int wgid = base + (orig >> 3);
    rowt = wgid / nct;
    colt = wgid - rowt * nct;
}

// ---------------- utility ----------------

__global__ void k_zero(float* __restrict__ p, long n) {
    long i = (long)blockIdx.x * 256 + threadIdx.x;
    long stride = (long)gridDim.x * 256;
    for (; i < n; i += stride) p[i] = 0.f;
}

// ---------------- degree / CSR ----------------

__global__ void k_hist(const int* __restrict__ dst, int* __restrict__ cnt, int E) {
    int e = blockIdx.x * 256 + threadIdx.x;
    if (e < E) atomicAdd(&cnt[dst[e]], 1);
}

// block scan: 1024 items/block (256 thr x 4)
__global__ __launch_bounds__(256) void k_scan1(const int* __restrict__ cnt,
                                               int* __restrict__ offs,
                                               int* __restrict__ bsum, int N) {
    __shared__ int ts[256];
    int b = blockIdx.x, t = threadIdx.x;
    int base = b * 1024 + t * 4;
    int v0 = (base + 0 < N) ? cnt[base + 0] : 0;
    int v1 = (base + 1 < N) ? cnt[base + 1] : 0;
    int v2 = (base + 2 < N) ? cnt[base + 2] : 0;
    int v3 = (base + 3 < N) ? cnt[base + 3] : 0;
    ts[t] = v0 + v1 + v2 + v3;
    __syncthreads();
    for (int off = 1; off < 256; off <<= 1) {
        int u = (t >= off) ? ts[t - off] : 0;
        __syncthreads();
        ts[t] += u;
        __syncthreads();
    }
    int ex = (t > 0) ? ts[t - 1] : 0;
    if (base + 0 < N) offs[base + 0] = ex;
    if (base + 1 < N) offs[base + 1] = ex + v0;
    if (base + 2 < N) offs[base + 2] = ex + v0 + v1;
    if (base + 3 < N) offs[base + 3] = ex + v0 + v1 + v2;
    if (t == 255) bsum[b] = ts[255];
}

__global__ __launch_bounds__(256) void k_scan2(int* __restrict__ bsum, int nb) {
    __shared__ int ts[256];
    int t = threadIdx.x;
    ts[t] = (t < nb) ? bsum[t] : 0;
    __syncthreads();
    for (int off = 1; off < 256; off <<= 1) {
        int u = (t >= off) ? ts[t - off] : 0;
        __syncthreads();
        ts[t] += u;
        __syncthreads();
    }
    if (t < nb) bsum[t] = (t > 0) ? ts[t - 1] : 0;
}

// also seeds cur = offs (for reorder's atomic cursor)
__global__ void k_scan3(int* __restrict__ offs, const int* __restrict__ bsum,
                        int* __restrict__ cur, int N) {
    int i = blockIdx.x * 256 + threadIdx.x;
    if (i < N) {
        int v = offs[i] + bsum[i >> 10];
        offs[i] = v;
        cur[i] = v;
    }
}

// reorder with inline weight: w = -rsqrt(deg[src]) * rsqrt(deg[dst])
__global__ void k_reorder2(const int* __restrict__ row, const int* __restrict__ col,
                           const int* __restrict__ cnt,
                           int* __restrict__ cur, int* __restrict__ srcS,
                           float* __restrict__ wS, int E) {
    int e = blockIdx.x * 256 + threadIdx.x;
    if (e < E) {
        int s = row[e], d = col[e];
        int p = atomicAdd(&cur[d], 1);
        float ds = (float)max(cnt[s], 1);
        float dd = (float)max(cnt[d], 1);
        srcS[p] = s;
        wS[p] = -rsqrtf(ds) * rsqrtf(dd);
    }
}

// ---------------- x -> Abf x-half (bf16 streaming convert) ----------------

__global__ void k_cvtX(const float* __restrict__ x, unsigned short* __restrict__ Abf,
                       int N) {
    int t = blockIdx.x * 256 + threadIdx.x;      // node*8 + sub
    int node = t >> 3, sub = t & 7;
    if (node >= N) return;
    bf16x8 o;
    #pragma unroll
    for (int j = 0; j < 8; ++j) {
        int c = sub * 8 + j;
        float v = (c < DIN) ? x[(size_t)node * DIN + c] : 0.f;
        o[j] = (short)f2bf(v);
    }
    *(bf16x8*)&Abf[(size_t)node * 128 + sub * 8] = o;
}

// ---------------- CSR segmented reductions ----------------

// agg1b: 8 lanes/node, gather bf16 x-half rows of Abf, write t1-half of Abf.
__global__ __launch_bounds__(256) void k_agg1b(const int* __restrict__ srcS,
                                               const float* __restrict__ wS,
                                               const int* __restrict__ offs,
                                               const int* __restrict__ cnt,
                                               unsigned short* __restrict__ Abf, int N) {
    int node = blockIdx.x * 32 + (threadIdx.x >> 3);
    int sub = threadIdx.x & 7;
    if (node >= N) return;
    int b0 = offs[node], b1 = b0 + cnt[node];
    float acc[8] = {};
    int i = b0;
    for (; i + 1 < b1; i += 2) {
        int s0 = srcS[i], s1 = srcS[i + 1];
        float w0 = wS[i], w1 = wS[i + 1];
        bf16x8 v0 = *(const bf16x8*)&Abf[(size_t)s0 * 128 + sub * 8];
        bf16x8 v1 = *(const bf16x8*)&Abf[(size_t)s1 * 128 + sub * 8];
        #pragma unroll
        for (int j = 0; j < 8; ++j)
            acc[j] += w0 * bf2f((unsigned short)v0[j]) + w1 * bf2f((unsigned short)v1[j]);
    }
    if (i < b1) {
        int s0 = srcS[i];
        float w0 = wS[i];
        bf16x8 v0 = *(const bf16x8*)&Abf[(size_t)s0 * 128 + sub * 8];
        #pragma unroll
        for (int j = 0; j < 8; ++j)
            acc[j] += w0 * bf2f((unsigned short)v0[j]);
    }
    bf16x8 o;
    #pragma unroll
    for (int j = 0; j < 8; ++j) o[j] = (short)f2bf(acc[j]);
    *(bf16x8*)&Abf[(size_t)node * 128 + 64 + sub * 8] = o;
}

// agg2y: per node (16 lanes): v = relu(x1p + segsum(w*hw1b) + c2b);
// xs = v + r1 (in-place over r1b); z = v + r2 (in-place over r2b);
// fused conv3 dots: out[node] = dot(xs,c3w0)+c3b ; y1[node] = dot(xs,c3w1).
__global__ __launch_bounds__(256) void k_agg2y(const unsigned short* __restrict__ hw1b,
                                               const int* __restrict__ srcS,
                                               const float* __restrict__ wS,
                                               const int* __restrict__ offs,
                                               const int* __restrict__ cnt,
                                               const float* __restrict__ c2b,
                                               const unsigned short* __restrict__ x1pb,
                                               unsigned short* __restrict__ rx1,   // r1b -> xsb
                                               unsigned short* __restrict__ rx2,   // r2b -> zb
                                               const float* __restrict__ c3w0,
                                               const float* __restrict__ c3w1,
                                               const float* __restrict__ c3b,
                                               float* __restrict__ out,
                                               float* __restrict__ y1,
                                               int N) {
    int node = blockIdx.x * 16 + (threadIdx.x >> 4);
    int k = threadIdx.x & 15;
    bool live = node < N;
    float acc[8] = {};
    int b0 = 0, b1 = 0;
    if (live) { b0 = offs[node]; b1 = b0 + cnt[node]; }
    int i = b0;
    for (; i + 1 < b1; i += 2) {
        int s0 = srcS[i], s1 = srcS[i + 1];
        float w0 = wS[i], w1 = wS[i + 1];
        bf16x8 v0 = *(const bf16x8*)&hw1b[(size_t)s0 * 128 + k * 8];
        bf16x8 v1 = *(const bf16x8*)&hw1b[(size_t)s1 * 128 + k * 8];
        #pragma unroll
        for (int j = 0; j < 8; ++j)
            acc[j] += w0 * bf2f((unsigned short)v0[j]) + w1 * bf2f((unsigned short)v1[j]);
    }
    if (i < b1) {
        int s0 = srcS[i];
        float w0 = wS[i];
        bf16x8 v0 = *(const bf16x8*)&hw1b[(size_t)s0 * 128 + k * 8];
        #pragma unroll
        for (int j = 0; j < 8; ++j)
            acc[j] += w0 * bf2f((unsigned short)v0[j]);
    }

    float a0 = 0.f, a1 = 0.f;
    if (live) {
        size_t base = (size_t)node * 128 + k * 8;
        bf16x8 x1v = *(const bf16x8*)&x1pb[base];
        bf16x8 r1v = *(const bf16x8*)&rx1[base];
        bf16x8 r2v = *(const bf16x8*)&rx2[base];
        bf16x8 xo, zo;
        int f0 = k * 8;
        #pragma unroll
        for (int j = 0; j < 8; ++j) {
            int f = f0 + j;
            float bias = (f < H2) ? c2b[f] : 0.f;
            float v = fmaxf(bf2f((unsigned short)x1v[j]) + acc[j] + bias, 0.f);
            float xsf = v + bf2f((unsigned short)r1v[j]);
            float zf  = v + bf2f((unsigned short)r2v[j]);
            xo[j] = (short)f2bf(xsf);
            zo[j] = (short)f2bf(zf);
            if (f < H2) {
                a0 += xsf * c3w0[f];
                a1 += xsf * c3w1[f];
            }
        }
        *(bf16x8*)&rx1[base] = xo;
        *(bf16x8*)&rx2[base] = zo;
    }
    // reduce across the 16 lanes of this node group (xor masks < 16 stay in-group)
    #pragma unroll
    for (int off = 8; off; off >>= 1) {
        a0 += __shfl_xor(a0, off);
        a1 += __shfl_xor(a1, off);
    }
    if (live && k == 0) {
        out[node] = a0 + c3b[0];
        y1[node]  = a1;
    }
}

// per node: out[node] += sum w*y1[src]
__global__ void k_agg3(const float* __restrict__ y1, const int* __restrict__ srcS,
                       const float* __restrict__ wS, const int* __restrict__ offs,
                       const int* __restrict__ cnt, float* __restrict__ out, int N) {
    int node = blockIdx.x * 256 + threadIdx.x;
    if (node >= N) return;
    int b0 = offs[node], b1 = b0 + cnt[node];
    float a = 0.f;
    for (int i = b0; i < b1; ++i) a += wS[i] * y1[srcS[i]];
    out[node] += a;
}

// ---------------- weight packs ----------------

// Bt1X [640][128]: j<300 -> [c1w0|c1w1] ; 384<=j<484 -> l1w ; 512<=j<612 -> l2w ; else 0
__global__ void k_packB1X(const float* __restrict__ w0, const float* __restrict__ w1,
                          const float* __restrict__ lw1, const float* __restrict__ lw2,
                          unsigned short* __restrict__ Bt) {
    int i = blockIdx.x * 256 + threadIdx.x;    // 640*128
    if (i >= 640 * 128) return;
    int j = i >> 7, k = i & 127;
    float v = 0.f;
    if (j < H1) {
        if (k < DIN) v = w0[(size_t)k * H1 + j];
        else if (k >= 64 && k < 64 + DIN) v = w1[(size_t)(k - 64) * H1 + j];
    } else if (j >= 384 && j < 384 + H2) {
        if (k < DIN) v = lw1[(size_t)k * H2 + (j - 384)];
    } else if (j >= 512 && j < 512 + H2) {
        if (k < DIN) v = lw2[(size_t)k * H2 + (j - 512)];
    }
    Bt[i] = f2bf(v);
}

// Bt2X [256][320]: j<100 -> c2w0 col j ; 128<=j<228 -> c2w1 col (j-128) ; else 0
__global__ void k_packB2X(const float* __restrict__ w0, const float* __restrict__ w1,
                          unsigned short* __restrict__ Bt) {
    int i = blockIdx.x * 256 + threadIdx.x;    // 256*320
    if (i >= 256 * 320) return;
    int j = i / 320, k = i % 320;
    float v = 0.f;
    if (k < H1) {
        if (j < H2) v = w0[(size_t)k * H2 + j];
        else if (j >= 128 && j < 128 + H2) v = w1[(size_t)k * H2 + (j - 128)];
    }
    Bt[i] = f2bf(v);
}

// ---------------- conv1+lin MFMA: A[M][128] @ Bt1X -> hC / r1b / r2b ----------------

__global__ __launch_bounds__(256) void gemm_c1(
    const unsigned short* __restrict__ A,
    const unsigned short* __restrict__ Bt,
    const float* __restrict__ c1b, const float* __restrict__ l1b,
    const float* __restrict__ l2b,
    unsigned short* __restrict__ hC,    // [M][320] chunk-relative
    unsigned short* __restrict__ r1p,   // already offset by r0*128
    unsigned short* __restrict__ r2p,
    int M)
{
    __shared__ unsigned short As[128][40];
    __shared__ unsigned short Bs[128][40];
    const int tid = threadIdx.x;
    const int wave = tid >> 6, lane = tid & 63;
    const int wr = wave >> 1, wc = wave & 1;
    int rowt, colt;
    xcd_tile(blockIdx.x, gridDim.x, 5, rowt, colt);
    const int row0 = rowt * 128;
    const int col0 = colt * 128;
    const int tr = tid >> 1;
    const int tk = (tid & 1) * 16;

    f32x4 acc[4][4] = {};

    for (int ks = 0; ks < 4; ++ks) {
        int kt = ks * 32;
        {
            int grow = row0 + tr;
            bf16x8 v0 = {}, v1 = {};
            if (grow < M) {
                const unsigned short* p = A + (size_t)grow * 128 + kt + tk;
                v0 = *(const bf16x8*)p;
                v1 = *(const bf16x8*)(p + 8);
            }
            *(bf16x8*)&As[tr][tk]     = v0;
            *(bf16x8*)&As[tr][tk + 8] = v1;
        }
        {
            int gcol = col0 + tr;
            const unsigned short* p = Bt + (size_t)gcol * 128 + kt + tk;
            *(bf16x8*)&Bs[tr][tk]     = *(const bf16x8*)p;
            *(bf16x8*)&Bs[tr][tk + 8] = *(const bf16x8*)(p + 8);
        }
        __syncthreads();

        const int kofs = (lane >> 4) * 8;
        bf16x8 af[4], bg[4];
        const int arow = wr * 64 + (lane & 15);
        const int bcol = wc * 64 + (lane & 15);
        #pragma unroll
        for (int m = 0; m < 4; ++m) af[m] = *(const bf16x8*)&As[arow + m * 16][kofs];
        #pragma unroll
        for (int n = 0; n < 4; ++n) bg[n] = *(const bf16x8*)&Bs[bcol + n * 16][kofs];
        #pragma unroll
        for (int m = 0; m < 4; ++m)
            #pragma unroll
            for (int n = 0; n < 4; ++n)
                acc[m][n] = __builtin_amdgcn_mfma_f32_16x16x32_bf16(af[m], bg[n], acc[m][n], 0, 0, 0);
        __syncthreads();
    }

    #pragma unroll
    for (int m = 0; m < 4; ++m) {
        #pragma unroll
        for (int n = 0; n < 4; ++n) {
            int col = col0 + wc * 64 + n * 16 + (lane & 15);
            #pragma unroll
            for (int i = 0; i < 4; ++i) {
                int row = row0 + wr * 64 + m * 16 + (lane >> 4) * 4 + i;
                if (row >= M) continue;
                float v = acc[m][n][i];
                if (col < 320) {
                    float ov = 0.f;
                    if (col < H1) ov = fmaxf(v + c1b[col], 0.f);
                    hC[(size_t)row * 320 + col] = f2bf(ov);
                } else if (col >= 384 && col < 512) {
                    int c = col - 384;
                    float ov = (c < H2) ? fmaxf(v + l1b[c], 0.f) : 0.f;
                    r1p[(size_t)row * 128 + c] = f2bf(ov);
                } else if (col >= 512) {
                    int c = col - 512;
                    float ov = (c < H2) ? fmaxf(v + l2b[c], 0.f) : 0.f;
                    r2p[(size_t)row * 128 + c] = f2bf(ov);
                }
            }
        }
    }
}

// ---------------- conv2 MFMA: hC[M][320] @ Bt2X -> x1pb / hw1b (both [*][128] bf16) ----

__global__ __launch_bounds__(256) void gemm_c2(
    const unsigned short* __restrict__ A,     // hC chunk
    const unsigned short* __restrict__ Bt,    // [256][320]
    unsigned short* __restrict__ x1p,         // offset r0*128
    unsigned short* __restrict__ hwp,         // offset r0*128
    int M)
{
    __shared__ unsigned short As[128][40];
    __shared__ unsigned short Bs[128][40];
    const int tid = threadIdx.x;
    const int wave = tid >> 6, lane = tid & 63;
    const int wr = wave >> 1, wc = wave & 1;
    int rowt, colt;
    xcd_tile(blockIdx.x, gridDim.x, 2, rowt, colt);
    const int row0 = rowt * 128;
    const int col0 = colt * 128;
    const int tr = tid >> 1;
    const int tk = (tid & 1) * 16;

    f32x4 acc[4][4] = {};

    for (int ks = 0; ks < 10; ++ks) {
        int kt = ks * 32;
        {
            int grow = row0 + tr;
            bf16x8 v0 = {}, v1 = {};
            if (grow < M) {
                const unsigned short* p = A + (size_t)grow * 320 + kt + tk;
                v0 = *(const bf16x8*)p;
                v1 = *(const bf16x8*)(p + 8);
            }
            *(bf16x8*)&As[tr][tk]     = v0;
            *(bf16x8*)&As[tr][tk + 8] = v1;
        }
        {
            int gcol = col0 + tr;
            const unsigned short* p = Bt + (size_t)gcol * 320 + kt + tk;
            *(bf16x8*)&Bs[tr][tk]     = *(const bf16x8*)p;
            *(bf16x8*)&Bs[tr][tk + 8] = *(const bf16x8*)(p + 8);
        }
        __syncthreads();

        const int kofs = (lane >> 4) * 8;
        bf16x8 af[4], bg[4];
        const int arow = wr * 64 + (lane & 15);
        const int bcol = wc * 64 + (lane & 15);
        #pragma unroll
        for (int m = 0; m < 4; ++m) af[m] = *(const bf16x8*)&As[arow + m * 16][kofs];
        #pragma unroll
        for (int n = 0; n < 4; ++n) bg[n] = *(const bf16x8*)&Bs[bcol + n * 16][kofs];
        #pragma unroll
        for (int m = 0; m < 4; ++m)
            #pragma unroll
            for (int n = 0; n < 4; ++n)
                acc[m][n] = __builtin_amdgcn_mfma_f32_16x16x32_bf16(af[m], bg[n], acc[m][n], 0, 0, 0);
        __syncthreads();
    }

    #pragma unroll
    for (int m = 0; m < 4; ++m) {
        #pragma unroll
        for (int n = 0; n < 4; ++n) {
            int col = col0 + wc * 64 + n * 16 + (lane & 15);
            #pragma unroll
            for (int i = 0; i < 4; ++i) {
                int row = row0 + wr * 64 + m * 16 + (lane >> 4) * 4 + i;
                if (row >= M) continue;
                float v = acc[m][n][i];
                if (col < 128) {
                    unsigned short o = (col < H2) ? f2bf(v) : (unsigned short)0;
                    x1p[(size_t)row * 128 + col] = o;
                } else {
                    int c = col - 128;   // matches Bt2X: c2w1 at rows 128..227
                    unsigned short o = (c < H2) ? f2bf(v) : (unsigned short)0;
                    hwp[(size_t)row * 128 + c] = o;
                }
            }
        }
    }
}

// ---------------- combined loss: grid-stride, per-block partials ----------------

__global__ __launch_bounds__(256) void k_loss2(const unsigned short* __restrict__ zb,
                                               const int* __restrict__ ei,
                                               const int* __restrict__ nei,
                                               int E, int En,
                                               float* __restrict__ part) {
    __shared__ float shP[4], shN[4];
    int k = threadIdx.x & 15;
    int grp = (blockIdx.x * 256 + threadIdx.x) >> 4;
    int ngrp = (gridDim.x * 256) >> 4;
    int tot = E + En;
    float sumP = 0.f, sumN = 0.f;

    for (int edge = grp; edge < tot; edge += ngrp) {
        int a, b;
        bool pos = edge < E;
        if (pos) { a = ei[edge]; b = ei[E + edge]; }
        else     { int e2 = edge - E; a = nei[e2]; b = nei[En + e2]; }
        bf16x8 va = *(const bf16x8*)&zb[(size_t)a * 128 + k * 8];
        bf16x8 vb = *(const bf16x8*)&zb[(size_t)b * 128 + k * 8];
        float d = 0.f;
        #pragma unroll
        for (int j = 0; j < 8; ++j)
            d += bf2f((unsigned short)va[j]) * bf2f((unsigned short)vb[j]);
        #pragma unroll
        for (int off = 8; off; off >>= 1) d += __shfl_xor(d, off);
        if (k == 0) {
            float s = 1.f / (1.f + expf(-d));
            if (pos) sumP += -logf(s + 1e-15f);
            else     sumN += -logf(1.f - s + 1e-15f);
        }
    }

    #pragma unroll
    for (int off = 32; off; off >>= 1) {
        sumP += __shfl_xor(sumP, off);
        sumN += __shfl_xor(sumN, off);
    }
    int wid = threadIdx.x >> 6;
    if ((threadIdx.x & 63) == 0) { shP[wid] = sumP; shN[wid] = sumN; }
    __syncthreads();
    if (threadIdx.x == 0)
        part[blockIdx.x * 2 + 0] = shP[0] + shP[1] + shP[2] + shP[3];
    if (threadIdx.x == 1)
        part[blockIdx.x * 2 + 1] = shN[0] + shN[1] + shN[2] + shN[3];
}

__global__ __launch_bounds__(256) void k_final2(const float* __restrict__ part, int nb,
                                                const float* __restrict__ c1,
                                                const float* __restrict__ c2,
                                                float* __restrict__ out, int N,
                                                float invEp, float invEn) {
    __shared__ float sp[4], sn[4];
    float aP = 0.f, aN = 0.f;
    for (int i = threadIdx.x; i < nb; i += 256) {
        aP += part[2 * i + 0];
        aN += part[2 * i + 1];
    }
    #pragma unroll
    for (int off = 32; off; off >>= 1) {
        aP += __shfl_xor(aP, off);
        aN += __shfl_xor(aN, off);
    }
    int wid = threadIdx.x >> 6;
    if ((threadIdx.x & 63) == 0) { sp[wid] = aP; sn[wid] = aN; }
    __syncthreads();
    if (threadIdx.x == 0) {
        float P = sp[0] + sp[1] + sp[2] + sp[3];
        float Nn = sn[0] + sn[1] + sn[2] + sn[3];
        out[N]     = P * invEp + Nn * invEn;
        out[N + 1] = c1[0];
        out[N + 2] = c2[0];
    }
}

// ---------------- launch ----------------

extern "C" void kernel_launch(void* const* d_in, const int* in_sizes, int n_in,
                              void* d_out, int out_size, void* d_ws, size_t ws_size,
                              hipStream_t stream) {
    const float* x   = (const float*)d_in[0];
    const int*   ei  = (const int*)d_in[1];
    const int*   nei = (const int*)d_in[2];
    const float* c1w0 = (const float*)d_in[3];
    const float* c1w1 = (const float*)d_in[4];
    const float* c1b  = (const float*)d_in[5];
    const float* c2w0 = (const float*)d_in[6];
    const float* c2w1 = (const float*)d_in[7];
    const float* c2b  = (const float*)d_in[8];
    const float* c3w0 = (const float*)d_in[9];
    const float* c3w1 = (const float*)d_in[10];
    const float* c3b  = (const float*)d_in[11];
    const float* l1w  = (const float*)d_in[12];
    const float* l1b  = (const float*)d_in[13];
    const float* l2w  = (const float*)d_in[14];
    const float* l2b  = (const float*)d_in[15];
    const float* c1s  = (const float*)d_in[16];
    const float* c2s  = (const float*)d_in[17];

    const int N  = in_sizes[0] / DIN;      // 100000
    const int E  = in_sizes[1] / 2;        // 262144
    const int En = in_sizes[2] / 2;        // 262144

    const int* row = ei;        // src
    const int* col = ei + E;    // dst

    // ---- workspace layout ----
    char* ws = (char*)d_ws;
    const size_t MB = 1024ull * 1024ull;
    const size_t KB = 1024ull;
    int*   srcS  = (int*)  (ws + 1 * MB);               // E i32 (1MiB)
    float* wS    = (float*)(ws + 2 * MB);               // E f32 (1MiB)
    int*   cnt   = (int*)  (ws + 3 * MB);               // N i32
    int*   offs  = (int*)  (ws + 3 * MB + 512 * KB);    // N i32
    int*   cur   = (int*)  (ws + 4 * MB);               // N i32
    float* y1    = (float*)(ws + 5 * MB);               // N f32 (0.4MiB)
    int*   bsum  = (int*)  (ws + 5 * MB + 416 * KB);    // 256 i32
    float* part  = (float*)(ws + 5 * MB + 420 * KB);    // 2048*2 f32 (16KB)
    unsigned short* Bt1X = (unsigned short*)(ws + 5 * MB + 448 * KB); // 640*128*2=160KB
    unsigned short* Bt2  = (unsigned short*)(ws + 5 * MB + 640 * KB); // 256*320*2=160KB
    unsigned short* Abf  = (unsigned short*)(ws + 6 * MB);    // N*128 bf16 (24.4MiB)
    unsigned short* r1b  = (unsigned short*)(ws + 31 * MB);   // N*128 bf16 -> xsb
    unsigned short* r2b  = (unsigned short*)(ws + 56 * MB);   // N*128 bf16 -> zb
    unsigned short* x1pb = (unsigned short*)(ws + 81 * MB);   // N*128 bf16
    unsigned short* hw1b = (unsigned short*)(ws + 106 * MB);  // N*128 bf16 -> 130.4
    unsigned short* hC   = (unsigned short*)(ws + 131 * MB);  // adaptive chunk [RC][320] bf16

    // adaptive GEMM chunk rows from actual workspace (deterministic)
    size_t hOff = 131 * MB;
    size_t avail = (ws_size > hOff + MB) ? (ws_size - hOff - MB) : 0;
    long maxRows = (long)(avail / 640);           // 320 cols * 2 B
    if (maxRows > N) maxRows = N;
    if (maxRows < 12500) maxRows = 12500;         // floor: 131+7.7 MiB, proven safe

    const int ZG = 1024;
    int gE = (E + 255) / 256;
    int gN = (N + 255) / 256;
    int NB = (N + 1023) / 1024;            // 98 <= 256

    // ---- degree histogram ----
    k_zero<<<ZG, 256, 0, stream>>>((float*)cnt, N);
    k_hist<<<gE, 256, 0, stream>>>(col, cnt, E);

    // ---- CSR build: scan (also seeds cur) + reorder-with-inline-weights ----
    k_scan1<<<NB, 256, 0, stream>>>(cnt, offs, bsum, N);
    k_scan2<<<1, 256, 0, stream>>>(bsum, NB);
    k_scan3<<<gN, 256, 0, stream>>>(offs, bsum, cur, N);
    k_reorder2<<<gE, 256, 0, stream>>>(row, col, cnt, cur, srcS, wS, E);

    // ---- weight packs (tiny) ----
    k_packB1X<<<(640 * 128 + 255) / 256, 256, 0, stream>>>(c1w0, c1w1, l1w, l2w, Bt1X);
    k_packB2X<<<(256 * 320 + 255) / 256, 256, 0, stream>>>(c2w0, c2w1, Bt2);

    // ---- x -> Abf x-half (bf16), then t1-half via bf16 CSR gather ----
    k_cvtX<<<(N * 8 + 255) / 256, 256, 0, stream>>>(x, Abf, N);
    k_agg1b<<<(N + 31) / 32, 256, 0, stream>>>(srcS, wS, offs, cnt, Abf, N);

    // ---- conv1(+lin) + conv2 MFMA, adaptive chunking (1 pass at ws>=192MiB) ----
    for (long r0 = 0; r0 < N; r0 += maxRows) {
        long rc = (N - r0 < maxRows) ? (N - r0) : maxRows;
        int nxt = (int)((rc + 127) / 128);
        gemm_c1<<<nxt * 5, 256, 0, stream>>>(Abf + (size_t)r0 * 128, Bt1X,
                                             c1b, l1b, l2b,
                                             hC, r1b + (size_t)r0 * 128, r2b + (size_t)r0 * 128,
                                             (int)rc);
        gemm_c2<<<nxt * 2, 256, 0, stream>>>(hC, Bt2,
                                             x1pb + (size_t)r0 * 128, hw1b + (size_t)r0 * 128,
                                             (int)rc);
    }

    // ---- fused conv2-aggregate + bias/relu + xs/z + conv3 dots ----
    k_agg2y<<<(N + 15) / 16, 256, 0, stream>>>(hw1b, srcS, wS, offs, cnt, c2b,
                                               x1pb, r1b, r2b,
                                               c3w0, c3w1, c3b, (float*)d_out, y1, N);

    // ---- conv3 aggregate: out[node] += segsum(w * y1[src]) ----
    k_agg3<<<gN, 256, 0, stream>>>(y1, srcS, wS, offs, cnt, (float*)d_out, N);

    // ---- combined loss: grid-stride, no same-address atomics ----
    const int LB = 2048;
    k_loss2<<<LB, 256, 0, stream>>>(r2b, ei, nei, E, En, part);
    k_final2<<<1, 256, 0, stream>>>(part, LB, c1s, c2s, (float*)d_out, N,
                                    1.0f / E, 1.0f / En);
}

// Round 18
// 292.975 us; speedup vs baseline: 1.4144x; 1.0858x over previous
//
#include <hip/hip_runtime.h>
#include <hip/hip_bf16.h>
#include <cstddef>

#define DIN 58
#define H1  300
#define H2  100

using bf16x8 = __attribute__((ext_vector_type(8))) short;
using f32x4  = __attribute__((ext_vector_type(4))) float;

__device__ inline unsigned short f2bf(float f) {
    union { float f; unsigned int u; } v; v.f = f;
    unsigned int r = v.u + 0x7fff + ((v.u >> 16) & 1);   // RNE
    return (unsigned short)(r >> 16);
}
__device__ inline float bf2f(unsigned short h) {
    union { unsigned int u; float f; } v; v.u = ((unsigned int)h) << 16;
    return v.f;
}

// bijective XCD-aware block swizzle (m204): blocks sharing an A row-tile
// land on the SAME XCD so its private L2 serves the repeats.
__device__ inline void xcd_tile(int orig, int nwg, int nct, int& rowt, int& colt) {
    int q = nwg >> 3, r = nwg & 7;
    int xcd = orig & 7;
    int base = (xcd < r) ? xcd * (q + 1) : r * (q + 1) + (xcd - r) * q;
    int wgid = base + (orig >> 3);
    rowt = wgid / nct;
    colt = wgid - rowt * nct;
}

// ---------------- utility ----------------

__global__ void k_zero(float* __restrict__ p, long n) {
    long i = (long)blockIdx.x * 256 + threadIdx.x;
    long stride = (long)gridDim.x * 256;
    for (; i < n; i += stride) p[i] = 0.f;
}

// ---------------- degree / CSR ----------------

__global__ void k_hist(const int* __restrict__ dst, int* __restrict__ cnt, int E) {
    int e = blockIdx.x * 256 + threadIdx.x;
    if (e < E) atomicAdd(&cnt[dst[e]], 1);
}

// block scan: 1024 items/block (256 thr x 4)
__global__ __launch_bounds__(256) void k_scan1(const int* __restrict__ cnt,
                                               int* __restrict__ offs,
                                               int* __restrict__ bsum, int N) {
    __shared__ int ts[256];
    int b = blockIdx.x, t = threadIdx.x;
    int base = b * 1024 + t * 4;
    int v0 = (base + 0 < N) ? cnt[base + 0] : 0;
    int v1 = (base + 1 < N) ? cnt[base + 1] : 0;
    int v2 = (base + 2 < N) ? cnt[base + 2] : 0;
    int v3 = (base + 3 < N) ? cnt[base + 3] : 0;
    ts[t] = v0 + v1 + v2 + v3;
    __syncthreads();
    for (int off = 1; off < 256; off <<= 1) {
        int u = (t >= off) ? ts[t - off] : 0;
        __syncthreads();
        ts[t] += u;
        __syncthreads();
    }
    int ex = (t > 0) ? ts[t - 1] : 0;
    if (base + 0 < N) offs[base + 0] = ex;
    if (base + 1 < N) offs[base + 1] = ex + v0;
    if (base + 2 < N) offs[base + 2] = ex + v0 + v1;
    if (base + 3 < N) offs[base + 3] = ex + v0 + v1 + v2;
    if (t == 255) bsum[b] = ts[255];
}

__global__ __launch_bounds__(256) void k_scan2(int* __restrict__ bsum, int nb) {
    __shared__ int ts[256];
    int t = threadIdx.x;
    ts[t] = (t < nb) ? bsum[t] : 0;
    __syncthreads();
    for (int off = 1; off < 256; off <<= 1) {
        int u = (t >= off) ? ts[t - off] : 0;
        __syncthreads();
        ts[t] += u;
        __syncthreads();
    }
    if (t < nb) bsum[t] = (t > 0) ? ts[t - 1] : 0;
}

// also seeds cur = offs (for reorder's atomic cursor)
__global__ void k_scan3(int* __restrict__ offs, const int* __restrict__ bsum,
                        int* __restrict__ cur, int N) {
    int i = blockIdx.x * 256 + threadIdx.x;
    if (i < N) {
        int v = offs[i] + bsum[i >> 10];
        offs[i] = v;
        cur[i] = v;
    }
}

// reorder with inline weight: w = -rsqrt(deg[src]) * rsqrt(deg[dst])
__global__ void k_reorder2(const int* __restrict__ row, const int* __restrict__ col,
                           const int* __restrict__ cnt,
                           int* __restrict__ cur, int* __restrict__ srcS,
                           float* __restrict__ wS, int E) {
    int e = blockIdx.x * 256 + threadIdx.x;
    if (e < E) {
        int s = row[e], d = col[e];
        int p = atomicAdd(&cur[d], 1);
        float ds = (float)max(cnt[s], 1);
        float dd = (float)max(cnt[d], 1);
        srcS[p] = s;
        wS[p] = -rsqrtf(ds) * rsqrtf(dd);
    }
}

// ---------------- x -> Abf x-half (bf16 streaming convert) ----------------

__global__ void k_cvtX(const float* __restrict__ x, unsigned short* __restrict__ Abf,
                       int N) {
    int t = blockIdx.x * 256 + threadIdx.x;      // node*8 + sub
    int node = t >> 3, sub = t & 7;
    if (node >= N) return;
    bf16x8 o;
    #pragma unroll
    for (int j = 0; j < 8; ++j) {
        int c = sub * 8 + j;
        float v = (c < DIN) ? x[(size_t)node * DIN + c] : 0.f;
        o[j] = (short)f2bf(v);
    }
    *(bf16x8*)&Abf[(size_t)node * 128 + sub * 8] = o;
}

// ---------------- CSR segmented reductions ----------------

// agg1b: 8 lanes/node, gather bf16 x-half rows of Abf, write t1-half of Abf.
__global__ __launch_bounds__(256) void k_agg1b(const int* __restrict__ srcS,
                                               const float* __restrict__ wS,
                                               const int* __restrict__ offs,
                                               const int* __restrict__ cnt,
                                               unsigned short* __restrict__ Abf, int N) {
    int node = blockIdx.x * 32 + (threadIdx.x >> 3);
    int sub = threadIdx.x & 7;
    if (node >= N) return;
    int b0 = offs[node], b1 = b0 + cnt[node];
    float acc[8] = {};
    int i = b0;
    for (; i + 1 < b1; i += 2) {
        int s0 = srcS[i], s1 = srcS[i + 1];
        float w0 = wS[i], w1 = wS[i + 1];
        bf16x8 v0 = *(const bf16x8*)&Abf[(size_t)s0 * 128 + sub * 8];
        bf16x8 v1 = *(const bf16x8*)&Abf[(size_t)s1 * 128 + sub * 8];
        #pragma unroll
        for (int j = 0; j < 8; ++j)
            acc[j] += w0 * bf2f((unsigned short)v0[j]) + w1 * bf2f((unsigned short)v1[j]);
    }
    if (i < b1) {
        int s0 = srcS[i];
        float w0 = wS[i];
        bf16x8 v0 = *(const bf16x8*)&Abf[(size_t)s0 * 128 + sub * 8];
        #pragma unroll
        for (int j = 0; j < 8; ++j)
            acc[j] += w0 * bf2f((unsigned short)v0[j]);
    }
    bf16x8 o;
    #pragma unroll
    for (int j = 0; j < 8; ++j) o[j] = (short)f2bf(acc[j]);
    *(bf16x8*)&Abf[(size_t)node * 128 + 64 + sub * 8] = o;
}

// agg2y: per node (16 lanes): v = relu(x1p + segsum(w*hw1b) + c2b);
// xs = v + r1 (in-place over r1b); z = v + r2 (in-place over r2b);
// fused conv3 dots: out[node] = dot(xs,c3w0)+c3b ; y1[node] = dot(xs,c3w1).
__global__ __launch_bounds__(256) void k_agg2y(const unsigned short* __restrict__ hw1b,
                                               const int* __restrict__ srcS,
                                               const float* __restrict__ wS,
                                               const int* __restrict__ offs,
                                               const int* __restrict__ cnt,
                                               const float* __restrict__ c2b,
                                               const unsigned short* __restrict__ x1pb,
                                               unsigned short* __restrict__ rx1,   // r1b -> xsb
                                               unsigned short* __restrict__ rx2,   // r2b -> zb
                                               const float* __restrict__ c3w0,
                                               const float* __restrict__ c3w1,
                                               const float* __restrict__ c3b,
                                               float* __restrict__ out,
                                               float* __restrict__ y1,
                                               int N) {
    int node = blockIdx.x * 16 + (threadIdx.x >> 4);
    int k = threadIdx.x & 15;
    bool live = node < N;
    float acc[8] = {};
    int b0 = 0, b1 = 0;
    if (live) { b0 = offs[node]; b1 = b0 + cnt[node]; }
    int i = b0;
    for (; i + 1 < b1; i += 2) {
        int s0 = srcS[i], s1 = srcS[i + 1];
        float w0 = wS[i], w1 = wS[i + 1];
        bf16x8 v0 = *(const bf16x8*)&hw1b[(size_t)s0 * 128 + k * 8];
        bf16x8 v1 = *(const bf16x8*)&hw1b[(size_t)s1 * 128 + k * 8];
        #pragma unroll
        for (int j = 0; j < 8; ++j)
            acc[j] += w0 * bf2f((unsigned short)v0[j]) + w1 * bf2f((unsigned short)v1[j]);
    }
    if (i < b1) {
        int s0 = srcS[i];
        float w0 = wS[i];
        bf16x8 v0 = *(const bf16x8*)&hw1b[(size_t)s0 * 128 + k * 8];
        #pragma unroll
        for (int j = 0; j < 8; ++j)
            acc[j] += w0 * bf2f((unsigned short)v0[j]);
    }

    float a0 = 0.f, a1 = 0.f;
    if (live) {
        size_t base = (size_t)node * 128 + k * 8;
        bf16x8 x1v = *(const bf16x8*)&x1pb[base];
        bf16x8 r1v = *(const bf16x8*)&rx1[base];
        bf16x8 r2v = *(const bf16x8*)&rx2[base];
        bf16x8 xo, zo;
        int f0 = k * 8;
        #pragma unroll
        for (int j = 0; j < 8; ++j) {
            int f = f0 + j;
            float bias = (f < H2) ? c2b[f] : 0.f;
            float v = fmaxf(bf2f((unsigned short)x1v[j]) + acc[j] + bias, 0.f);
            float xsf = v + bf2f((unsigned short)r1v[j]);
            float zf  = v + bf2f((unsigned short)r2v[j]);
            xo[j] = (short)f2bf(xsf);
            zo[j] = (short)f2bf(zf);
            if (f < H2) {
                a0 += xsf * c3w0[f];
                a1 += xsf * c3w1[f];
            }
        }
        *(bf16x8*)&rx1[base] = xo;
        *(bf16x8*)&rx2[base] = zo;
    }
    // reduce across the 16 lanes of this node group (xor masks < 16 stay in-group)
    #pragma unroll
    for (int off = 8; off; off >>= 1) {
        a0 += __shfl_xor(a0, off);
        a1 += __shfl_xor(a1, off);
    }
    if (live && k == 0) {
        out[node] = a0 + c3b[0];
        y1[node]  = a1;
    }
}

// per node: out[node] += sum w*y1[src]
__global__ void k_agg3(const float* __restrict__ y1, const int* __restrict__ srcS,
                       const float* __restrict__ wS, const int* __restrict__ offs,
                       const int* __restrict__ cnt, float* __restrict__ out, int N) {
    int node = blockIdx.x * 256 + threadIdx.x;
    if (node >= N) return;
    int b0 = offs[node], b1 = b0 + cnt[node];
    float a = 0.f;
    for (int i = b0; i < b1; ++i) a += wS[i] * y1[srcS[i]];
    out[node] += a;
}

// ---------------- weight packs ----------------

// Bt1X [640][128]: j<300 -> [c1w0|c1w1] ; 384<=j<484 -> l1w ; 512<=j<612 -> l2w ; else 0
__global__ void k_packB1X(const float* __restrict__ w0, const float* __restrict__ w1,
                          const float* __restrict__ lw1, const float* __restrict__ lw2,
                          unsigned short* __restrict__ Bt) {
    int i = blockIdx.x * 256 + threadIdx.x;    // 640*128
    if (i >= 640 * 128) return;
    int j = i >> 7, k = i & 127;
    float v = 0.f;
    if (j < H1) {
        if (k < DIN) v = w0[(size_t)k * H1 + j];
        else if (k >= 64 && k < 64 + DIN) v = w1[(size_t)(k - 64) * H1 + j];
    } else if (j >= 384 && j < 384 + H2) {
        if (k < DIN) v = lw1[(size_t)k * H2 + (j - 384)];
    } else if (j >= 512 && j < 512 + H2) {
        if (k < DIN) v = lw2[(size_t)k * H2 + (j - 512)];
    }
    Bt[i] = f2bf(v);
}

// Bt2X [256][320]: j<100 -> c2w0 col j ; 128<=j<228 -> c2w1 col (j-128) ; else 0
__global__ void k_packB2X(const float* __restrict__ w0, const float* __restrict__ w1,
                          unsigned short* __restrict__ Bt) {
    int i = blockIdx.x * 256 + threadIdx.x;    // 256*320
    if (i >= 256 * 320) return;
    int j = i / 320, k = i % 320;
    float v = 0.f;
    if (k < H1) {
        if (j < H2) v = w0[(size_t)k * H2 + j];
        else if (j >= 128 && j < 128 + H2) v = w1[(size_t)k * H2 + (j - 128)];
    }
    Bt[i] = f2bf(v);
}

// ---------------- conv1+lin MFMA (64x128 tile): A[M][128] @ Bt1X -> hC/r1b/r2b ----

__global__ __launch_bounds__(256) void gemm_c1(
    const unsigned short* __restrict__ A,
    const unsigned short* __restrict__ Bt,
    const float* __restrict__ c1b, const float* __restrict__ l1b,
    const float* __restrict__ l2b,
    unsigned short* __restrict__ hC,    // [M][320] chunk-relative
    unsigned short* __restrict__ r1p,   // already offset by r0*128
    unsigned short* __restrict__ r2p,
    int M)
{
    __shared__ unsigned short As[64][40];
    __shared__ unsigned short Bs[128][40];
    const int tid = threadIdx.x;
    const int wave = tid >> 6, lane = tid & 63;
    const int wr = wave >> 1, wc = wave & 1;
    int rowt, colt;
    xcd_tile(blockIdx.x, gridDim.x, 5, rowt, colt);
    const int row0 = rowt * 64;
    const int col0 = colt * 128;

    f32x4 acc[2][4] = {};

    for (int ks = 0; ks < 4; ++ks) {
        int kt = ks * 32;
        {   // A tile: 64 rows x 32 k = 256 bf16x8 chunks, 1/thread
            int r = tid >> 2, k8 = (tid & 3) * 8;
            bf16x8 v = {};
            int grow = row0 + r;
            if (grow < M) v = *(const bf16x8*)(A + (size_t)grow * 128 + kt + k8);
            *(bf16x8*)&As[r][k8] = v;
        }
        #pragma unroll
        for (int q = 0; q < 2; ++q) {   // B tile: 128 cols x 32 k = 512 chunks, 2/thread
            int idx = tid + q * 256;
            int gcol = idx >> 2, k8 = (idx & 3) * 8;
            *(bf16x8*)&Bs[gcol][k8] =
                *(const bf16x8*)(Bt + (size_t)(col0 + gcol) * 128 + kt + k8);
        }
        __syncthreads();

        const int kofs = (lane >> 4) * 8;
        bf16x8 af[2], bg[4];
        const int arow = wr * 32 + (lane & 15);
        const int bcol = wc * 64 + (lane & 15);
        #pragma unroll
        for (int m = 0; m < 2; ++m) af[m] = *(const bf16x8*)&As[arow + m * 16][kofs];
        #pragma unroll
        for (int n = 0; n < 4; ++n) bg[n] = *(const bf16x8*)&Bs[bcol + n * 16][kofs];
        #pragma unroll
        for (int m = 0; m < 2; ++m)
            #pragma unroll
            for (int n = 0; n < 4; ++n)
                acc[m][n] = __builtin_amdgcn_mfma_f32_16x16x32_bf16(af[m], bg[n], acc[m][n], 0, 0, 0);
        __syncthreads();
    }

    #pragma unroll
    for (int m = 0; m < 2; ++m) {
        #pragma unroll
        for (int n = 0; n < 4; ++n) {
            int col = col0 + wc * 64 + n * 16 + (lane & 15);
            #pragma unroll
            for (int i = 0; i < 4; ++i) {
                int row = row0 + wr * 32 + m * 16 + (lane >> 4) * 4 + i;
                if (row >= M) continue;
                float v = acc[m][n][i];
                if (col < 320) {
                    float ov = 0.f;
                    if (col < H1) ov = fmaxf(v + c1b[col], 0.f);
                    hC[(size_t)row * 320 + col] = f2bf(ov);
                } else if (col >= 384 && col < 512) {
                    int c = col - 384;
                    float ov = (c < H2) ? fmaxf(v + l1b[c], 0.f) : 0.f;
                    r1p[(size_t)row * 128 + c] = f2bf(ov);
                } else if (col >= 512) {
                    int c = col - 512;
                    float ov = (c < H2) ? fmaxf(v + l2b[c], 0.f) : 0.f;
                    r2p[(size_t)row * 128 + c] = f2bf(ov);
                }
            }
        }
    }
}

// ---------------- conv2 MFMA (64x128 tile): hC[M][320] @ Bt2X -> x1pb/hw1b ----

__global__ __launch_bounds__(256) void gemm_c2(
    const unsigned short* __restrict__ A,     // hC chunk
    const unsigned short* __restrict__ Bt,    // [256][320]
    unsigned short* __restrict__ x1p,         // offset r0*128
    unsigned short* __restrict__ hwp,         // offset r0*128
    int M)
{
    __shared__ unsigned short As[64][40];
    __shared__ unsigned short Bs[128][40];
    const int tid = threadIdx.x;
    const int wave = tid >> 6, lane = tid & 63;
    const int wr = wave >> 1, wc = wave & 1;
    int rowt, colt;
    xcd_tile(blockIdx.x, gridDim.x, 2, rowt, colt);
    const int row0 = rowt * 64;
    const int col0 = colt * 128;

    f32x4 acc[2][4] = {};

    for (int ks = 0; ks < 10; ++ks) {
        int kt = ks * 32;
        {
            int r = tid >> 2, k8 = (tid & 3) * 8;
            bf16x8 v = {};
            int grow = row0 + r;
            if (grow < M) v = *(const bf16x8*)(A + (size_t)grow * 320 + kt + k8);
            *(bf16x8*)&As[r][k8] = v;
        }
        #pragma unroll
        for (int q = 0; q < 2; ++q) {
            int idx = tid + q * 256;
            int gcol = idx >> 2, k8 = (idx & 3) * 8;
            *(bf16x8*)&Bs[gcol][k8] =
                *(const bf16x8*)(Bt + (size_t)(col0 + gcol) * 320 + kt + k8);
        }
        __syncthreads();

        const int kofs = (lane >> 4) * 8;
        bf16x8 af[2], bg[4];
        const int arow = wr * 32 + (lane & 15);
        const int bcol = wc * 64 + (lane & 15);
        #pragma unroll
        for (int m = 0; m < 2; ++m) af[m] = *(const bf16x8*)&As[arow + m * 16][kofs];
        #pragma unroll
        for (int n = 0; n < 4; ++n) bg[n] = *(const bf16x8*)&Bs[bcol + n * 16][kofs];
        #pragma unroll
        for (int m = 0; m < 2; ++m)
            #pragma unroll
            for (int n = 0; n < 4; ++n)
                acc[m][n] = __builtin_amdgcn_mfma_f32_16x16x32_bf16(af[m], bg[n], acc[m][n], 0, 0, 0);
        __syncthreads();
    }

    #pragma unroll
    for (int m = 0; m < 2; ++m) {
        #pragma unroll
        for (int n = 0; n < 4; ++n) {
            int col = col0 + wc * 64 + n * 16 + (lane & 15);
            #pragma unroll
            for (int i = 0; i < 4; ++i) {
                int row = row0 + wr * 32 + m * 16 + (lane >> 4) * 4 + i;
                if (row >= M) continue;
                float v = acc[m][n][i];
                if (col < 128) {
                    unsigned short o = (col < H2) ? f2bf(v) : (unsigned short)0;
                    x1p[(size_t)row * 128 + col] = o;
                } else {
                    int c = col - 128;   // matches Bt2X: c2w1 at rows 128..227
                    unsigned short o = (c < H2) ? f2bf(v) : (unsigned short)0;
                    hwp[(size_t)row * 128 + c] = o;
                }
            }
        }
    }
}

// ---------------- combined loss: grid-stride, per-block partials ----------------

__global__ __launch_bounds__(256) void k_loss2(const unsigned short* __restrict__ zb,
                                               const int* __restrict__ ei,
                                               const int* __restrict__ nei,
                                               int E, int En,
                                               float* __restrict__ part) {
    __shared__ float shP[4], shN[4];
    int k = threadIdx.x & 15;
    int grp = (blockIdx.x * 256 + threadIdx.x) >> 4;
    int ngrp = (gridDim.x * 256) >> 4;
    int tot = E + En;
    float sumP = 0.f, sumN = 0.f;

    for (int edge = grp; edge < tot; edge += ngrp) {
        int a, b;
        bool pos = edge < E;
        if (pos) { a = ei[edge]; b = ei[E + edge]; }
        else     { int e2 = edge - E; a = nei[e2]; b = nei[En + e2]; }
        bf16x8 va = *(const bf16x8*)&zb[(size_t)a * 128 + k * 8];
        bf16x8 vb = *(const bf16x8*)&zb[(size_t)b * 128 + k * 8];
        float d = 0.f;
        #pragma unroll
        for (int j = 0; j < 8; ++j)
            d += bf2f((unsigned short)va[j]) * bf2f((unsigned short)vb[j]);
        #pragma unroll
        for (int off = 8; off; off >>= 1) d += __shfl_xor(d, off);
        if (k == 0) {
            float s = 1.f / (1.f + expf(-d));
            if (pos) sumP += -logf(s + 1e-15f);
            else     sumN += -logf(1.f - s + 1e-15f);
        }
    }

    #pragma unroll
    for (int off = 32; off; off >>= 1) {
        sumP += __shfl_xor(sumP, off);
        sumN += __shfl_xor(sumN, off);
    }
    int wid = threadIdx.x >> 6;
    if ((threadIdx.x & 63) == 0) { shP[wid] = sumP; shN[wid] = sumN; }
    __syncthreads();
    if (threadIdx.x == 0)
        part[blockIdx.x * 2 + 0] = shP[0] + shP[1] + shP[2] + shP[3];
    if (threadIdx.x == 1)
        part[blockIdx.x * 2 + 1] = shN[0] + shN[1] + shN[2] + shN[3];
}

__global__ __launch_bounds__(256) void k_final2(const float* __restrict__ part, int nb,
                                                const float* __restrict__ c1,
                                                const float* __restrict__ c2,
                                                float* __restrict__ out, int N,
                                                float invEp, float invEn) {
    __shared__ float sp[4], sn[4];
    float aP = 0.f, aN = 0.f;
    for (int i = threadIdx.x; i < nb; i += 256) {
        aP += part[2 * i + 0];
        aN += part[2 * i + 1];
    }
    #pragma unroll
    for (int off = 32; off; off >>= 1) {
        aP += __shfl_xor(aP, off);
        aN += __shfl_xor(aN, off);
    }
    int wid = threadIdx.x >> 6;
    if ((threadIdx.x & 63) == 0) { sp[wid] = aP; sn[wid] = aN; }
    __syncthreads();
    if (threadIdx.x == 0) {
        float P = sp[0] + sp[1] + sp[2] + sp[3];
        float Nn = sn[0] + sn[1] + sn[2] + sn[3];
        out[N]     = P * invEp + Nn * invEn;
        out[N + 1] = c1[0];
        out[N + 2] = c2[0];
    }
}

// ---------------- launch ----------------

extern "C" void kernel_launch(void* const* d_in, const int* in_sizes, int n_in,
                              void* d_out, int out_size, void* d_ws, size_t ws_size,
                              hipStream_t stream) {
    const float* x   = (const float*)d_in[0];
    const int*   ei  = (const int*)d_in[1];
    const int*   nei = (const int*)d_in[2];
    const float* c1w0 = (const float*)d_in[3];
    const float* c1w1 = (const float*)d_in[4];
    const float* c1b  = (const float*)d_in[5];
    const float* c2w0 = (const float*)d_in[6];
    const float* c2w1 = (const float*)d_in[7];
    const float* c2b  = (const float*)d_in[8];
    const float* c3w0 = (const float*)d_in[9];
    const float* c3w1 = (const float*)d_in[10];
    const float* c3b  = (const float*)d_in[11];
    const float* l1w  = (const float*)d_in[12];
    const float* l1b  = (const float*)d_in[13];
    const float* l2w  = (const float*)d_in[14];
    const float* l2b  = (const float*)d_in[15];
    const float* c1s  = (const float*)d_in[16];
    const float* c2s  = (const float*)d_in[17];

    const int N  = in_sizes[0] / DIN;      // 100000
    const int E  = in_sizes[1] / 2;        // 262144
    const int En = in_sizes[2] / 2;        // 262144

    const int* row = ei;        // src
    const int* col = ei + E;    // dst

    // ---- workspace layout ----
    char* ws = (char*)d_ws;
    const size_t MB = 1024ull * 1024ull;
    const size_t KB = 1024ull;
    int*   srcS  = (int*)  (ws + 1 * MB);               // E i32 (1MiB)
    float* wS    = (float*)(ws + 2 * MB);               // E f32 (1MiB)
    int*   cnt   = (int*)  (ws + 3 * MB);               // N i32
    int*   offs  = (int*)  (ws + 3 * MB + 512 * KB);    // N i32
    int*   cur   = (int*)  (ws + 4 * MB);               // N i32
    float* y1    = (float*)(ws + 5 * MB);               // N f32 (0.4MiB)
    int*   bsum  = (int*)  (ws + 5 * MB + 416 * KB);    // 256 i32
    float* part  = (float*)(ws + 5 * MB + 420 * KB);    // 2048*2 f32 (16KB)
    unsigned short* Bt1X = (unsigned short*)(ws + 5 * MB + 448 * KB); // 640*128*2=160KB
    unsigned short* Bt2  = (unsigned short*)(ws + 5 * MB + 640 * KB); // 256*320*2=160KB
    unsigned short* Abf  = (unsigned short*)(ws + 6 * MB);    // N*128 bf16 (24.4MiB)
    unsigned short* r1b  = (unsigned short*)(ws + 31 * MB);   // N*128 bf16 -> xsb
    unsigned short* r2b  = (unsigned short*)(ws + 56 * MB);   // N*128 bf16 -> zb
    unsigned short* x1pb = (unsigned short*)(ws + 81 * MB);   // N*128 bf16
    unsigned short* hw1b = (unsigned short*)(ws + 106 * MB);  // N*128 bf16 -> 130.4
    unsigned short* hC   = (unsigned short*)(ws + 131 * MB);  // adaptive chunk [RC][320] bf16

    // adaptive GEMM chunk rows from actual workspace (deterministic)
    size_t hOff = 131 * MB;
    size_t avail = (ws_size > hOff + MB) ? (ws_size - hOff - MB) : 0;
    long maxRows = (long)(avail / 640);           // 320 cols * 2 B
    if (maxRows > N) maxRows = N;
    if (maxRows < 12500) maxRows = 12500;         // floor: 131+7.7 MiB, proven safe

    const int ZG = 1024;
    int gE = (E + 255) / 256;
    int gN = (N + 255) / 256;
    int NB = (N + 1023) / 1024;            // 98 <= 256

    // ---- degree histogram ----
    k_zero<<<ZG, 256, 0, stream>>>((float*)cnt, N);
    k_hist<<<gE, 256, 0, stream>>>(col, cnt, E);

    // ---- CSR build: scan (also seeds cur) + reorder-with-inline-weights ----
    k_scan1<<<NB, 256, 0, stream>>>(cnt, offs, bsum, N);
    k_scan2<<<1, 256, 0, stream>>>(bsum, NB);
    k_scan3<<<gN, 256, 0, stream>>>(offs, bsum, cur, N);
    k_reorder2<<<gE, 256, 0, stream>>>(row, col, cnt, cur, srcS, wS, E);

    // ---- weight packs (tiny) ----
    k_packB1X<<<(640 * 128 + 255) / 256, 256, 0, stream>>>(c1w0, c1w1, l1w, l2w, Bt1X);
    k_packB2X<<<(256 * 320 + 255) / 256, 256, 0, stream>>>(c2w0, c2w1, Bt2);

    // ---- x -> Abf x-half (bf16), then t1-half via bf16 CSR gather ----
    k_cvtX<<<(N * 8 + 255) / 256, 256, 0, stream>>>(x, Abf, N);
    k_agg1b<<<(N + 31) / 32, 256, 0, stream>>>(srcS, wS, offs, cnt, Abf, N);

    // ---- conv1(+lin) + conv2 MFMA, 64-row tiles, XCD-swizzled 1-D grids ----
    for (long r0 = 0; r0 < N; r0 += maxRows) {
        long rc = (N - r0 < maxRows) ? (N - r0) : maxRows;
        int nrt = (int)((rc + 63) / 64);
        gemm_c1<<<nrt * 5, 256, 0, stream>>>(Abf + (size_t)r0 * 128, Bt1X,
                                             c1b, l1b, l2b,
                                             hC, r1b + (size_t)r0 * 128, r2b + (size_t)r0 * 128,
                                             (int)rc);
        gemm_c2<<<nrt * 2, 256, 0, stream>>>(hC, Bt2,
                                             x1pb + (size_t)r0 * 128, hw1b + (size_t)r0 * 128,
                                             (int)rc);
    }

    // ---- fused conv2-aggregate + bias/relu + xs/z + conv3 dots ----
    k_agg2y<<<(N + 15) / 16, 256, 0, stream>>>(hw1b, srcS, wS, offs, cnt, c2b,
                                               x1pb, r1b, r2b,
                                               c3w0, c3w1, c3b, (float*)d_out, y1, N);

    // ---- conv3 aggregate: out[node] += segsum(w * y1[src]) ----
    k_agg3<<<gN, 256, 0, stream>>>(y1, srcS, wS, offs, cnt, (float*)d_out, N);

    // ---- combined loss: grid-stride, no same-address atomics ----
    const int LB = 2048;
    k_loss2<<<LB, 256, 0, stream>>>(r2b, ei, nei, E, En, part);
    k_final2<<<1, 256, 0, stream>>>(part, LB, c1s, c2s, (float*)d_out, N,
                                    1.0f / E, 1.0f / En);
}

// Round 19
// 289.870 us; speedup vs baseline: 1.4296x; 1.0107x over previous
//
#include <hip/hip_runtime.h>
#include <hip/hip_bf16.h>
#include <cstddef>

#define DIN 58
#define H1  300
#define H2  100

using bf16x8 = __attribute__((ext_vector_type(8))) short;
using f32x4  = __attribute__((ext_vector_type(4))) float;

__device__ inline unsigned short f2bf(float f) {
    union { float f; unsigned int u; } v; v.f = f;
    unsigned int r = v.u + 0x7fff + ((v.u >> 16) & 1);   // RNE
    return (unsigned short)(r >> 16);
}
__device__ inline float bf2f(unsigned short h) {
    union { unsigned int u; float f; } v; v.u = ((unsigned int)h) << 16;
    return v.f;
}

// bijective XCD-aware block swizzle (m204)
__device__ inline void xcd_tile(int orig, int nwg, int nct, int& rowt, int& colt) {
    int q = nwg >> 3, r = nwg & 7;
    int xcd = orig & 7;
    int base = (xcd < r) ? xcd * (q + 1) : r * (q + 1) + (xcd - r) * q;
    int wgid = base + (orig >> 3);
    rowt = wgid / nct;
    colt = wgid - rowt * nct;
}

// ---------------- utility ----------------

__global__ void k_zero(float* __restrict__ p, long n) {
    long i = (long)blockIdx.x * 256 + threadIdx.x;
    long stride = (long)gridDim.x * 256;
    for (; i < n; i += stride) p[i] = 0.f;
}

// ---------------- degree / CSR ----------------

__global__ void k_hist(const int* __restrict__ dst, int* __restrict__ cnt, int E) {
    int e = blockIdx.x * 256 + threadIdx.x;
    if (e < E) atomicAdd(&cnt[dst[e]], 1);
}

// block scan: 1024 items/block (256 thr x 4)
__global__ __launch_bounds__(256) void k_scan1(const int* __restrict__ cnt,
                                               int* __restrict__ offs,
                                               int* __restrict__ bsum, int N) {
    __shared__ int ts[256];
    int b = blockIdx.x, t = threadIdx.x;
    int base = b * 1024 + t * 4;
    int v0 = (base + 0 < N) ? cnt[base + 0] : 0;
    int v1 = (base + 1 < N) ? cnt[base + 1] : 0;
    int v2 = (base + 2 < N) ? cnt[base + 2] : 0;
    int v3 = (base + 3 < N) ? cnt[base + 3] : 0;
    ts[t] = v0 + v1 + v2 + v3;
    __syncthreads();
    for (int off = 1; off < 256; off <<= 1) {
        int u = (t >= off) ? ts[t - off] : 0;
        __syncthreads();
        ts[t] += u;
        __syncthreads();
    }
    int ex = (t > 0) ? ts[t - 1] : 0;
    if (base + 0 < N) offs[base + 0] = ex;
    if (base + 1 < N) offs[base + 1] = ex + v0;
    if (base + 2 < N) offs[base + 2] = ex + v0 + v1;
    if (base + 3 < N) offs[base + 3] = ex + v0 + v1 + v2;
    if (t == 255) bsum[b] = ts[255];
}

__global__ __launch_bounds__(256) void k_scan2(int* __restrict__ bsum, int nb) {
    __shared__ int ts[256];
    int t = threadIdx.x;
    ts[t] = (t < nb) ? bsum[t] : 0;
    __syncthreads();
    for (int off = 1; off < 256; off <<= 1) {
        int u = (t >= off) ? ts[t - off] : 0;
        __syncthreads();
        ts[t] += u;
        __syncthreads();
    }
    if (t < nb) bsum[t] = (t > 0) ? ts[t - 1] : 0;
}

// also seeds cur = offs (for reorder's atomic cursor)
__global__ void k_scan3(int* __restrict__ offs, const int* __restrict__ bsum,
                        int* __restrict__ cur, int N) {
    int i = blockIdx.x * 256 + threadIdx.x;
    if (i < N) {
        int v = offs[i] + bsum[i >> 10];
        offs[i] = v;
        cur[i] = v;
    }
}

// reorder with inline weight: w = -rsqrt(deg[src]) * rsqrt(deg[dst])
__global__ void k_reorder2(const int* __restrict__ row, const int* __restrict__ col,
                           const int* __restrict__ cnt,
                           int* __restrict__ cur, int* __restrict__ srcS,
                           float* __restrict__ wS, int E) {
    int e = blockIdx.x * 256 + threadIdx.x;
    if (e < E) {
        int s = row[e], d = col[e];
        int p = atomicAdd(&cur[d], 1);
        float ds = (float)max(cnt[s], 1);
        float dd = (float)max(cnt[d], 1);
        srcS[p] = s;
        wS[p] = -rsqrtf(ds) * rsqrtf(dd);
    }
}

// ---------------- x -> Abf x-half (bf16 streaming convert) ----------------

__global__ void k_cvtX(const float* __restrict__ x, unsigned short* __restrict__ Abf,
                       int N) {
    int t = blockIdx.x * 256 + threadIdx.x;      // node*8 + sub
    int node = t >> 3, sub = t & 7;
    if (node >= N) return;
    bf16x8 o;
    #pragma unroll
    for (int j = 0; j < 8; ++j) {
        int c = sub * 8 + j;
        float v = (c < DIN) ? x[(size_t)node * DIN + c] : 0.f;
        o[j] = (short)f2bf(v);
    }
    *(bf16x8*)&Abf[(size_t)node * 128 + sub * 8] = o;
}

// ---------------- CSR segmented reductions (4-wide load-issue batches) ----------------

// agg1b: 8 lanes/node, gather bf16 x-half rows of Abf, write t1-half of Abf.
__global__ __launch_bounds__(256) void k_agg1b(const int* __restrict__ srcS,
                                               const float* __restrict__ wS,
                                               const int* __restrict__ offs,
                                               const int* __restrict__ cnt,
                                               unsigned short* __restrict__ Abf, int N) {
    int node = blockIdx.x * 32 + (threadIdx.x >> 3);
    int sub = threadIdx.x & 7;
    if (node >= N) return;
    int b0 = offs[node], b1 = b0 + cnt[node];
    float acc[8] = {};
    for (int i = b0; i < b1; i += 4) {
        int r = b1 - i;
        int s0 = srcS[i];
        int s1 = (r > 1) ? srcS[i + 1] : s0;
        int s2 = (r > 2) ? srcS[i + 2] : s0;
        int s3 = (r > 3) ? srcS[i + 3] : s0;
        float w0 = wS[i];
        float w1 = (r > 1) ? wS[i + 1] : 0.f;
        float w2 = (r > 2) ? wS[i + 2] : 0.f;
        float w3 = (r > 3) ? wS[i + 3] : 0.f;
        bf16x8 v0 = *(const bf16x8*)&Abf[(size_t)s0 * 128 + sub * 8];
        bf16x8 v1 = *(const bf16x8*)&Abf[(size_t)s1 * 128 + sub * 8];
        bf16x8 v2 = *(const bf16x8*)&Abf[(size_t)s2 * 128 + sub * 8];
        bf16x8 v3 = *(const bf16x8*)&Abf[(size_t)s3 * 128 + sub * 8];
        #pragma unroll
        for (int j = 0; j < 8; ++j)
            acc[j] += w0 * bf2f((unsigned short)v0[j]) + w1 * bf2f((unsigned short)v1[j])
                    + w2 * bf2f((unsigned short)v2[j]) + w3 * bf2f((unsigned short)v3[j]);
    }
    bf16x8 o;
    #pragma unroll
    for (int j = 0; j < 8; ++j) o[j] = (short)f2bf(acc[j]);
    *(bf16x8*)&Abf[(size_t)node * 128 + 64 + sub * 8] = o;
}

// agg2y: per node (16 lanes): v = relu(x1p + segsum(w*hw1b) + c2b);
// xs = v + r1 (in-place over r1b); z = v + r2 (in-place over r2b);
// fused conv3 dots: out[node] = dot(xs,c3w0)+c3b ; y1[node] = dot(xs,c3w1).
__global__ __launch_bounds__(256) void k_agg2y(const unsigned short* __restrict__ hw1b,
                                               const int* __restrict__ srcS,
                                               const float* __restrict__ wS,
                                               const int* __restrict__ offs,
                                               const int* __restrict__ cnt,
                                               const float* __restrict__ c2b,
                                               const unsigned short* __restrict__ x1pb,
                                               unsigned short* __restrict__ rx1,   // r1b -> xsb
                                               unsigned short* __restrict__ rx2,   // r2b -> zb
                                               const float* __restrict__ c3w0,
                                               const float* __restrict__ c3w1,
                                               const float* __restrict__ c3b,
                                               float* __restrict__ out,
                                               float* __restrict__ y1,
                                               int N) {
    int node = blockIdx.x * 16 + (threadIdx.x >> 4);
    int k = threadIdx.x & 15;
    bool live = node < N;
    float acc[8] = {};
    int b0 = 0, b1 = 0;
    if (live) { b0 = offs[node]; b1 = b0 + cnt[node]; }
    for (int i = b0; i < b1; i += 4) {
        int r = b1 - i;
        int s0 = srcS[i];
        int s1 = (r > 1) ? srcS[i + 1] : s0;
        int s2 = (r > 2) ? srcS[i + 2] : s0;
        int s3 = (r > 3) ? srcS[i + 3] : s0;
        float w0 = wS[i];
        float w1 = (r > 1) ? wS[i + 1] : 0.f;
        float w2 = (r > 2) ? wS[i + 2] : 0.f;
        float w3 = (r > 3) ? wS[i + 3] : 0.f;
        bf16x8 v0 = *(const bf16x8*)&hw1b[(size_t)s0 * 128 + k * 8];
        bf16x8 v1 = *(const bf16x8*)&hw1b[(size_t)s1 * 128 + k * 8];
        bf16x8 v2 = *(const bf16x8*)&hw1b[(size_t)s2 * 128 + k * 8];
        bf16x8 v3 = *(const bf16x8*)&hw1b[(size_t)s3 * 128 + k * 8];
        #pragma unroll
        for (int j = 0; j < 8; ++j)
            acc[j] += w0 * bf2f((unsigned short)v0[j]) + w1 * bf2f((unsigned short)v1[j])
                    + w2 * bf2f((unsigned short)v2[j]) + w3 * bf2f((unsigned short)v3[j]);
    }

    float a0 = 0.f, a1 = 0.f;
    if (live) {
        size_t base = (size_t)node * 128 + k * 8;
        bf16x8 x1v = *(const bf16x8*)&x1pb[base];
        bf16x8 r1v = *(const bf16x8*)&rx1[base];
        bf16x8 r2v = *(const bf16x8*)&rx2[base];
        bf16x8 xo, zo;
        int f0 = k * 8;
        #pragma unroll
        for (int j = 0; j < 8; ++j) {
            int f = f0 + j;
            float bias = (f < H2) ? c2b[f] : 0.f;
            float v = fmaxf(bf2f((unsigned short)x1v[j]) + acc[j] + bias, 0.f);
            float xsf = v + bf2f((unsigned short)r1v[j]);
            float zf  = v + bf2f((unsigned short)r2v[j]);
            xo[j] = (short)f2bf(xsf);
            zo[j] = (short)f2bf(zf);
            if (f < H2) {
                a0 += xsf * c3w0[f];
                a1 += xsf * c3w1[f];
            }
        }
        *(bf16x8*)&rx1[base] = xo;
        *(bf16x8*)&rx2[base] = zo;
    }
    // reduce across the 16 lanes of this node group (xor masks < 16 stay in-group)
    #pragma unroll
    for (int off = 8; off; off >>= 1) {
        a0 += __shfl_xor(a0, off);
        a1 += __shfl_xor(a1, off);
    }
    if (live && k == 0) {
        out[node] = a0 + c3b[0];
        y1[node]  = a1;
    }
}

// per node: out[node] += sum w*y1[src]  (4-wide issue)
__global__ void k_agg3(const float* __restrict__ y1, const int* __restrict__ srcS,
                       const float* __restrict__ wS, const int* __restrict__ offs,
                       const int* __restrict__ cnt, float* __restrict__ out, int N) {
    int node = blockIdx.x * 256 + threadIdx.x;
    if (node >= N) return;
    int b0 = offs[node], b1 = b0 + cnt[node];
    float a = 0.f;
    for (int i = b0; i < b1; i += 4) {
        int r = b1 - i;
        int s0 = srcS[i];
        int s1 = (r > 1) ? srcS[i + 1] : s0;
        int s2 = (r > 2) ? srcS[i + 2] : s0;
        int s3 = (r > 3) ? srcS[i + 3] : s0;
        float w0 = wS[i];
        float w1 = (r > 1) ? wS[i + 1] : 0.f;
        float w2 = (r > 2) ? wS[i + 2] : 0.f;
        float w3 = (r > 3) ? wS[i + 3] : 0.f;
        a += w0 * y1[s0] + w1 * y1[s1] + w2 * y1[s2] + w3 * y1[s3];
    }
    out[node] += a;
}

// ---------------- weight packs ----------------

// Bt1X [640][128]: j<300 -> [c1w0|c1w1] ; 384<=j<484 -> l1w ; 512<=j<612 -> l2w ; else 0
__global__ void k_packB1X(const float* __restrict__ w0, const float* __restrict__ w1,
                          const float* __restrict__ lw1, const float* __restrict__ lw2,
                          unsigned short* __restrict__ Bt) {
    int i = blockIdx.x * 256 + threadIdx.x;    // 640*128
    if (i >= 640 * 128) return;
    int j = i >> 7, k = i & 127;
    float v = 0.f;
    if (j < H1) {
        if (k < DIN) v = w0[(size_t)k * H1 + j];
        else if (k >= 64 && k < 64 + DIN) v = w1[(size_t)(k - 64) * H1 + j];
    } else if (j >= 384 && j < 384 + H2) {
        if (k < DIN) v = lw1[(size_t)k * H2 + (j - 384)];
    } else if (j >= 512 && j < 512 + H2) {
        if (k < DIN) v = lw2[(size_t)k * H2 + (j - 512)];
    }
    Bt[i] = f2bf(v);
}

// Bt2X [256][320]: j<100 -> c2w0 col j ; 128<=j<228 -> c2w1 col (j-128) ; else 0
__global__ void k_packB2X(const float* __restrict__ w0, const float* __restrict__ w1,
                          unsigned short* __restrict__ Bt) {
    int i = blockIdx.x * 256 + threadIdx.x;    // 256*320
    if (i >= 256 * 320) return;
    int j = i / 320, k = i % 320;
    float v = 0.f;
    if (k < H1) {
        if (j < H2) v = w0[(size_t)k * H2 + j];
        else if (j >= 128 && j < 128 + H2) v = w1[(size_t)k * H2 + (j - 128)];
    }
    Bt[i] = f2bf(v);
}

// ---------------- conv1+lin MFMA (64x128 tile): A[M][128] @ Bt1X -> hC/r1b/r2b ----

__global__ __launch_bounds__(256) void gemm_c1(
    const unsigned short* __restrict__ A,
    const unsigned short* __restrict__ Bt,
    const float* __restrict__ c1b, const float* __restrict__ l1b,
    const float* __restrict__ l2b,
    unsigned short* __restrict__ hC,    // [M][320] chunk-relative
    unsigned short* __restrict__ r1p,   // already offset by r0*128
    unsigned short* __restrict__ r2p,
    int M)
{
    __shared__ unsigned short As[64][40];
    __shared__ unsigned short Bs[128][40];
    const int tid = threadIdx.x;
    const int wave = tid >> 6, lane = tid & 63;
    const int wr = wave >> 1, wc = wave & 1;
    int rowt, colt;
    xcd_tile(blockIdx.x, gridDim.x, 5, rowt, colt);
    const int row0 = rowt * 64;
    const int col0 = colt * 128;

    f32x4 acc[2][4] = {};

    for (int ks = 0; ks < 4; ++ks) {
        int kt = ks * 32;
        {   // A tile: 64 rows x 32 k = 256 bf16x8 chunks, 1/thread
            int r = tid >> 2, k8 = (tid & 3) * 8;
            bf16x8 v = {};
            int grow = row0 + r;
            if (grow < M) v = *(const bf16x8*)(A + (size_t)grow * 128 + kt + k8);
            *(bf16x8*)&As[r][k8] = v;
        }
        #pragma unroll
        for (int q = 0; q < 2; ++q) {   // B tile: 128 cols x 32 k = 512 chunks, 2/thread
            int idx = tid + q * 256;
            int gcol = idx >> 2, k8 = (idx & 3) * 8;
            *(bf16x8*)&Bs[gcol][k8] =
                *(const bf16x8*)(Bt + (size_t)(col0 + gcol) * 128 + kt + k8);
        }
        __syncthreads();

        const int kofs = (lane >> 4) * 8;
        bf16x8 af[2], bg[4];
        const int arow = wr * 32 + (lane & 15);
        const int bcol = wc * 64 + (lane & 15);
        #pragma unroll
        for (int m = 0; m < 2; ++m) af[m] = *(const bf16x8*)&As[arow + m * 16][kofs];
        #pragma unroll
        for (int n = 0; n < 4; ++n) bg[n] = *(const bf16x8*)&Bs[bcol + n * 16][kofs];
        #pragma unroll
        for (int m = 0; m < 2; ++m)
            #pragma unroll
            for (int n = 0; n < 4; ++n)
                acc[m][n] = __builtin_amdgcn_mfma_f32_16x16x32_bf16(af[m], bg[n], acc[m][n], 0, 0, 0);
        __syncthreads();
    }

    #pragma unroll
    for (int m = 0; m < 2; ++m) {
        #pragma unroll
        for (int n = 0; n < 4; ++n) {
            int col = col0 + wc * 64 + n * 16 + (lane & 15);
            #pragma unroll
            for (int i = 0; i < 4; ++i) {
                int row = row0 + wr * 32 + m * 16 + (lane >> 4) * 4 + i;
                if (row >= M) continue;
                float v = acc[m][n][i];
                if (col < 320) {
                    float ov = 0.f;
                    if (col < H1) ov = fmaxf(v + c1b[col], 0.f);
                    hC[(size_t)row * 320 + col] = f2bf(ov);
                } else if (col >= 384 && col < 512) {
                    int c = col - 384;
                    float ov = (c < H2) ? fmaxf(v + l1b[c], 0.f) : 0.f;
                    r1p[(size_t)row * 128 + c] = f2bf(ov);
                } else if (col >= 512) {
                    int c = col - 512;
                    float ov = (c < H2) ? fmaxf(v + l2b[c], 0.f) : 0.f;
                    r2p[(size_t)row * 128 + c] = f2bf(ov);
                }
            }
        }
    }
}

// ---------------- conv2 MFMA (64x128 tile): hC[M][320] @ Bt2X -> x1pb/hw1b ----

__global__ __launch_bounds__(256) void gemm_c2(
    const unsigned short* __restrict__ A,     // hC chunk
    const unsigned short* __restrict__ Bt,    // [256][320]
    unsigned short* __restrict__ x1p,         // offset r0*128
    unsigned short* __restrict__ hwp,         // offset r0*128
    int M)
{
    __shared__ unsigned short As[64][40];
    __shared__ unsigned short Bs[128][40];
    const int tid = threadIdx.x;
    const int wave = tid >> 6, lane = tid & 63;
    const int wr = wave >> 1, wc = wave & 1;
    int rowt, colt;
    xcd_tile(blockIdx.x, gridDim.x, 2, rowt, colt);
    const int row0 = rowt * 64;
    const int col0 = colt * 128;

    f32x4 acc[2][4] = {};

    for (int ks = 0; ks < 10; ++ks) {
        int kt = ks * 32;
        {
            int r = tid >> 2, k8 = (tid & 3) * 8;
            bf16x8 v = {};
            int grow = row0 + r;
            if (grow < M) v = *(const bf16x8*)(A + (size_t)grow * 320 + kt + k8);
            *(bf16x8*)&As[r][k8] = v;
        }
        #pragma unroll
        for (int q = 0; q < 2; ++q) {
            int idx = tid + q * 256;
            int gcol = idx >> 2, k8 = (idx & 3) * 8;
            *(bf16x8*)&Bs[gcol][k8] =
                *(const bf16x8*)(Bt + (size_t)(col0 + gcol) * 320 + kt + k8);
        }
        __syncthreads();

        const int kofs = (lane >> 4) * 8;
        bf16x8 af[2], bg[4];
        const int arow = wr * 32 + (lane & 15);
        const int bcol = wc * 64 + (lane & 15);
        #pragma unroll
        for (int m = 0; m < 2; ++m) af[m] = *(const bf16x8*)&As[arow + m * 16][kofs];
        #pragma unroll
        for (int n = 0; n < 4; ++n) bg[n] = *(const bf16x8*)&Bs[bcol + n * 16][kofs];
        #pragma unroll
        for (int m = 0; m < 2; ++m)
            #pragma unroll
            for (int n = 0; n < 4; ++n)
                acc[m][n] = __builtin_amdgcn_mfma_f32_16x16x32_bf16(af[m], bg[n], acc[m][n], 0, 0, 0);
        __syncthreads();
    }

    #pragma unroll
    for (int m = 0; m < 2; ++m) {
        #pragma unroll
        for (int n = 0; n < 4; ++n) {
            int col = col0 + wc * 64 + n * 16 + (lane & 15);
            #pragma unroll
            for (int i = 0; i < 4; ++i) {
                int row = row0 + wr * 32 + m * 16 + (lane >> 4) * 4 + i;
                if (row >= M) continue;
                float v = acc[m][n][i];
                if (col < 128) {
                    unsigned short o = (col < H2) ? f2bf(v) : (unsigned short)0;
                    x1p[(size_t)row * 128 + col] = o;
                } else {
                    int c = col - 128;   // matches Bt2X: c2w1 at rows 128..227
                    unsigned short o = (c < H2) ? f2bf(v) : (unsigned short)0;
                    hwp[(size_t)row * 128 + c] = o;
                }
            }
        }
    }
}

// ---------------- combined loss: grid-stride, per-block partials ----------------

__global__ __launch_bounds__(256) void k_loss2(const unsigned short* __restrict__ zb,
                                               const int* __restrict__ ei,
                                               const int* __restrict__ nei,
                                               int E, int En,
                                               float* __restrict__ part) {
    __shared__ float shP[4], shN[4];
    int k = threadIdx.x & 15;
    int grp = (blockIdx.x * 256 + threadIdx.x) >> 4;
    int ngrp = (gridDim.x * 256) >> 4;
    int tot = E + En;
    float sumP = 0.f, sumN = 0.f;

    for (int edge = grp; edge < tot; edge += ngrp) {
        int a, b;
        bool pos = edge < E;
        if (pos) { a = ei[edge]; b = ei[E + edge]; }
        else     { int e2 = edge - E; a = nei[e2]; b = nei[En + e2]; }
        bf16x8 va = *(const bf16x8*)&zb[(size_t)a * 128 + k * 8];
        bf16x8 vb = *(const bf16x8*)&zb[(size_t)b * 128 + k * 8];
        float d = 0.f;
        #pragma unroll
        for (int j = 0; j < 8; ++j)
            d += bf2f((unsigned short)va[j]) * bf2f((unsigned short)vb[j]);
        #pragma unroll
        for (int off = 8; off; off >>= 1) d += __shfl_xor(d, off);
        if (k == 0) {
            float s = 1.f / (1.f + expf(-d));
            if (pos) sumP += -logf(s + 1e-15f);
            else     sumN += -logf(1.f - s + 1e-15f);
        }
    }

    #pragma unroll
    for (int off = 32; off; off >>= 1) {
        sumP += __shfl_xor(sumP, off);
        sumN += __shfl_xor(sumN, off);
    }
    int wid = threadIdx.x >> 6;
    if ((threadIdx.x & 63) == 0) { shP[wid] = sumP; shN[wid] = sumN; }
    __syncthreads();
    if (threadIdx.x == 0)
        part[blockIdx.x * 2 + 0] = shP[0] + shP[1] + shP[2] + shP[3];
    if (threadIdx.x == 1)
        part[blockIdx.x * 2 + 1] = shN[0] + shN[1] + shN[2] + shN[3];
}

__global__ __launch_bounds__(256) void k_final2(const float* __restrict__ part, int nb,
                                                const float* __restrict__ c1,
                                                const float* __restrict__ c2,
                                                float* __restrict__ out, int N,
                                                float invEp, float invEn) {
    __shared__ float sp[4], sn[4];
    float aP = 0.f, aN = 0.f;
    for (int i = threadIdx.x; i < nb; i += 256) {
        aP += part[2 * i + 0];
        aN += part[2 * i + 1];
    }
    #pragma unroll
    for (int off = 32; off; off >>= 1) {
        aP += __shfl_xor(aP, off);
        aN += __shfl_xor(aN, off);
    }
    int wid = threadIdx.x >> 6;
    if ((threadIdx.x & 63) == 0) { sp[wid] = aP; sn[wid] = aN; }
    __syncthreads();
    if (threadIdx.x == 0) {
        float P = sp[0] + sp[1] + sp[2] + sp[3];
        float Nn = sn[0] + sn[1] + sn[2] + sn[3];
        out[N]     = P * invEp + Nn * invEn;
        out[N + 1] = c1[0];
        out[N + 2] = c2[0];
    }
}

// ---------------- launch ----------------

extern "C" void kernel_launch(void* const* d_in, const int* in_sizes, int n_in,
                              void* d_out, int out_size, void* d_ws, size_t ws_size,
                              hipStream_t stream) {
    const float* x   = (const float*)d_in[0];
    const int*   ei  = (const int*)d_in[1];
    const int*   nei = (const int*)d_in[2];
    const float* c1w0 = (const float*)d_in[3];
    const float* c1w1 = (const float*)d_in[4];
    const float* c1b  = (const float*)d_in[5];
    const float* c2w0 = (const float*)d_in[6];
    const float* c2w1 = (const float*)d_in[7];
    const float* c2b  = (const float*)d_in[8];
    const float* c3w0 = (const float*)d_in[9];
    const float* c3w1 = (const float*)d_in[10];
    const float* c3b  = (const float*)d_in[11];
    const float* l1w  = (const float*)d_in[12];
    const float* l1b  = (const float*)d_in[13];
    const float* l2w  = (const float*)d_in[14];
    const float* l2b  = (const float*)d_in[15];
    const float* c1s  = (const float*)d_in[16];
    const float* c2s  = (const float*)d_in[17];

    const int N  = in_sizes[0] / DIN;      // 100000
    const int E  = in_sizes[1] / 2;        // 262144
    const int En = in_sizes[2] / 2;        // 262144

    const int* row = ei;        // src
    const int* col = ei + E;    // dst

    // ---- workspace layout ----
    char* ws = (char*)d_ws;
    const size_t MB = 1024ull * 1024ull;
    const size_t KB = 1024ull;
    int*   srcS  = (int*)  (ws + 1 * MB);               // E i32 (1MiB)
    float* wS    = (float*)(ws + 2 * MB);               // E f32 (1MiB)
    int*   cnt   = (int*)  (ws + 3 * MB);               // N i32
    int*   offs  = (int*)  (ws + 3 * MB + 512 * KB);    // N i32
    int*   cur   = (int*)  (ws + 4 * MB);               // N i32
    float* y1    = (float*)(ws + 5 * MB);               // N f32 (0.4MiB)
    int*   bsum  = (int*)  (ws + 5 * MB + 416 * KB);    // 256 i32
    float* part  = (float*)(ws + 5 * MB + 420 * KB);    // 2048*2 f32 (16KB)
    unsigned short* Bt1X = (unsigned short*)(ws + 5 * MB + 448 * KB); // 640*128*2=160KB
    unsigned short* Bt2  = (unsigned short*)(ws + 5 * MB + 640 * KB); // 256*320*2=160KB
    unsigned short* Abf  = (unsigned short*)(ws + 6 * MB);    // N*128 bf16 (24.4MiB)
    unsigned short* r1b  = (unsigned short*)(ws + 31 * MB);   // N*128 bf16 -> xsb
    unsigned short* r2b  = (unsigned short*)(ws + 56 * MB);   // N*128 bf16 -> zb
    unsigned short* x1pb = (unsigned short*)(ws + 81 * MB);   // N*128 bf16
    unsigned short* hw1b = (unsigned short*)(ws + 106 * MB);  // N*128 bf16 -> 130.4
    unsigned short* hC   = (unsigned short*)(ws + 131 * MB);  // adaptive chunk [RC][320] bf16

    // adaptive GEMM chunk rows from actual workspace (deterministic)
    size_t hOff = 131 * MB;
    size_t avail = (ws_size > hOff + MB) ? (ws_size - hOff - MB) : 0;
    long maxRows = (long)(avail / 640);           // 320 cols * 2 B
    if (maxRows > N) maxRows = N;
    if (maxRows < 12500) maxRows = 12500;         // floor: 131+7.7 MiB, proven safe

    const int ZG = 1024;
    int gE = (E + 255) / 256;
    int gN = (N + 255) / 256;
    int NB = (N + 1023) / 1024;            // 98 <= 256

    // ---- degree histogram ----
    k_zero<<<ZG, 256, 0, stream>>>((float*)cnt, N);
    k_hist<<<gE, 256, 0, stream>>>(col, cnt, E);

    // ---- CSR build: scan (also seeds cur) + reorder-with-inline-weights ----
    k_scan1<<<NB, 256, 0, stream>>>(cnt, offs, bsum, N);
    k_scan2<<<1, 256, 0, stream>>>(bsum, NB);
    k_scan3<<<gN, 256, 0, stream>>>(offs, bsum, cur, N);
    k_reorder2<<<gE, 256, 0, stream>>>(row, col, cnt, cur, srcS, wS, E);

    // ---- weight packs (tiny) ----
    k_packB1X<<<(640 * 128 + 255) / 256, 256, 0, stream>>>(c1w0, c1w1, l1w, l2w, Bt1X);
    k_packB2X<<<(256 * 320 + 255) / 256, 256, 0, stream>>>(c2w0, c2w1, Bt2);

    // ---- x -> Abf x-half (bf16), then t1-half via bf16 CSR gather ----
    k_cvtX<<<(N * 8 + 255) / 256, 256, 0, stream>>>(x, Abf, N);
    k_agg1b<<<(N + 31) / 32, 256, 0, stream>>>(srcS, wS, offs, cnt, Abf, N);

    // ---- conv1(+lin) + conv2 MFMA, 64-row tiles, XCD-swizzled 1-D grids ----
    for (long r0 = 0; r0 < N; r0 += maxRows) {
        long rc = (N - r0 < maxRows) ? (N - r0) : maxRows;
        int nrt = (int)((rc + 63) / 64);
        gemm_c1<<<nrt * 5, 256, 0, stream>>>(Abf + (size_t)r0 * 128, Bt1X,
                                             c1b, l1b, l2b,
                                             hC, r1b + (size_t)r0 * 128, r2b + (size_t)r0 * 128,
                                             (int)rc);
        gemm_c2<<<nrt * 2, 256, 0, stream>>>(hC, Bt2,
                                             x1pb + (size_t)r0 * 128, hw1b + (size_t)r0 * 128,
                                             (int)rc);
    }

    // ---- fused conv2-aggregate + bias/relu + xs/z + conv3 dots ----
    k_agg2y<<<(N + 15) / 16, 256, 0, stream>>>(hw1b, srcS, wS, offs, cnt, c2b,
                                               x1pb, r1b, r2b,
                                               c3w0, c3w1, c3b, (float*)d_out, y1, N);

    // ---- conv3 aggregate: out[node] += segsum(w * y1[src]) ----
    k_agg3<<<gN, 256, 0, stream>>>(y1, srcS, wS, offs, cnt, (float*)d_out, N);

    // ---- combined loss: grid-stride, no same-address atomics ----
    const int LB = 2048;
    k_loss2<<<LB, 256, 0, stream>>>(r2b, ei, nei, E, En, part);
    k_final2<<<1, 256, 0, stream>>>(part, LB, c1s, c2s, (float*)d_out, N,
                                    1.0f / E, 1.0f / En);
}